// Round 2
// baseline (571.688 us; speedup 1.0000x reference)
//
#include <hip/hip_runtime.h>

// ---------------------------------------------------------------------------
// PhysNet stack, MI355X.
//   proto[i] = h_self[i] + fmtab[i] * (S[i] @ W_gate),
//   S[i] = sum of radial rows over all pair-slots hitting atom i (module-invariant)
// S via counting-sort + gather (no fp32 atomics). Module chain = 16 GEMMs with
// double-buffered weight staging (prefetch overlapped with MFMA) and ping-pong
// activation buffers (one barrier per stage, no read/write race).
// ---------------------------------------------------------------------------

#define LN2F 0.69314718055994530942f
#define MOD_STRIDE (15 * 16384 + 8192) // 15 FxF mats + 1 gate (64x128) per module

using short8  = __attribute__((ext_vector_type(8))) short;
using float4v = __attribute__((ext_vector_type(4))) float;

__device__ __forceinline__ float sspf(float x) {
  float ax = fabsf(x);
  return fmaxf(x, 0.0f) + __logf(1.0f + __expf(-ax)) - LN2F;
}

__device__ __forceinline__ unsigned short f2bf(float x) {
  unsigned int u = __float_as_uint(x);
  u += 0x7fffu + ((u >> 16) & 1u);
  return (unsigned short)(u >> 16);
}

// ---------------------------------------------------------------------------
// S = segmented sum of radial rows: hist -> scan -> place -> gather
// ---------------------------------------------------------------------------
__global__ __launch_bounds__(256) void hist_kernel(const int* __restrict__ idx,
                                                   unsigned int* __restrict__ cnt, int n2p) {
  int i = blockIdx.x * 256 + threadIdx.x;
  int stride = gridDim.x * 256;
  for (; i < n2p; i += stride) atomicAdd(&cnt[idx[i]], 1u);
}

__global__ __launch_bounds__(256) void scan_kernel(const unsigned int* __restrict__ cnt,
                                                   unsigned int* __restrict__ off,
                                                   unsigned int* __restrict__ cur, int NA) {
  // NA == 8192 == 256 threads * 32 bins
  int t = threadIdx.x;
  unsigned int local[32], s = 0;
#pragma unroll
  for (int i = 0; i < 32; ++i) { local[i] = cnt[t * 32 + i]; s += local[i]; }
  unsigned int v = s;
  int lane = t & 63, w = t >> 6;
#pragma unroll
  for (int o = 1; o < 64; o <<= 1) {
    unsigned int u = __shfl_up(v, o, 64);
    if (lane >= o) v += u;
  }
  __shared__ unsigned int wt4[4];
  if (lane == 63) wt4[w] = v;
  __syncthreads();
  unsigned int base = 0;
  for (int k = 0; k < w; ++k) base += wt4[k];
  unsigned int excl = base + v - s;
#pragma unroll
  for (int i = 0; i < 32; ++i) {
    off[t * 32 + i] = excl;
    cur[t * 32 + i] = excl;
    excl += local[i];
  }
  if (t == 255) off[NA] = excl;
}

__global__ __launch_bounds__(256) void place_kernel(const int* __restrict__ idx,
                                                    unsigned int* __restrict__ cur,
                                                    unsigned int* __restrict__ pairid, int P) {
  int i = blockIdx.x * 256 + threadIdx.x;
  int stride = gridDim.x * 256;
  int n2p = 2 * P;
  for (; i < n2p; i += stride) {
    int a = idx[i];
    unsigned int pos = atomicAdd(&cur[a], 1u);
    pairid[pos] = (i >= P) ? (unsigned int)(i - P) : (unsigned int)i;
  }
}

__global__ __launch_bounds__(256) void gather_kernel(const float* __restrict__ radial,
                                                     const unsigned int* __restrict__ off,
                                                     const unsigned int* __restrict__ pairid,
                                                     float* __restrict__ S) {
  __shared__ float red[3][64];
  int a = blockIdx.x;
  int lane = threadIdx.x & 63, w = threadIdx.x >> 6;
  unsigned int b = off[a], e = off[a + 1];
  float acc = 0.0f;
  for (unsigned int j = b + w; j < e; j += 4) {
    unsigned int p = pairid[j];
    acc += radial[(size_t)p * 64 + lane];
  }
  if (w > 0) red[w - 1][lane] = acc;
  __syncthreads();
  if (w == 0) {
    acc += red[0][lane] + red[1][lane] + red[2][lane];
    S[(size_t)a * 64 + lane] = acc;
  }
}

// ---------------------------------------------------------------------------
// Weight prep: transpose fp32 W[k][n] -> bf16 Wt[n][k]
// ---------------------------------------------------------------------------
struct PrepArgs {
  const float* src[80];
  int off[80];
  int isgate[80];
  int nmats;
};

__global__ __launch_bounds__(256) void prep_weights(PrepArgs A, unsigned short* __restrict__ Wt) {
  int m = blockIdx.x;
  const float* s = A.src[m];
  unsigned short* d = Wt + A.off[m];
  if (!A.isgate[m]) {
    for (int i = threadIdx.x; i < 16384; i += 256) {
      int k = i >> 7, n = i & 127;
      d[n * 128 + k] = f2bf(s[i]);
    }
  } else {
    for (int i = threadIdx.x; i < 8192; i += 256) {
      int k = i >> 7, n = i & 127;
      d[n * 64 + k] = f2bf(s[i]);
    }
  }
}

// ---------------------------------------------------------------------------
// Module kernel
// ---------------------------------------------------------------------------
struct ModArgs {
  const float* feat_in;
  float* feat_out;
  const float* S;
  const unsigned short* wt;
  const float* bias[17];   // 0..14 per-mat biases; 15=gvec; 16=W_out
  const float* b_out;
  float* energy;
  int first;
};

__device__ __forceinline__ void gemm128(const unsigned short* sA_, const unsigned short* sW,
                                        int arow, int c, int l16, int quad, float4v acc[4]) {
  const unsigned short* ar = sA_ + (arow + l16) * 136 + quad * 8;
  short8 a0 = *(const short8*)(ar);
  short8 a1 = *(const short8*)(ar + 32);
  short8 a2 = *(const short8*)(ar + 64);
  short8 a3 = *(const short8*)(ar + 96);
#pragma unroll
  for (int f = 0; f < 4; ++f) {
    const unsigned short* br = sW + (64 * c + 16 * f + l16) * 136 + quad * 8;
    acc[f] = __builtin_amdgcn_mfma_f32_16x16x32_bf16(a0, *(const short8*)(br), acc[f], 0, 0, 0);
    acc[f] = __builtin_amdgcn_mfma_f32_16x16x32_bf16(a1, *(const short8*)(br + 32), acc[f], 0, 0, 0);
    acc[f] = __builtin_amdgcn_mfma_f32_16x16x32_bf16(a2, *(const short8*)(br + 64), acc[f], 0, 0, 0);
    acc[f] = __builtin_amdgcn_mfma_f32_16x16x32_bf16(a3, *(const short8*)(br + 96), acc[f], 0, 0, 0);
  }
}

__device__ __forceinline__ void gemm64(const unsigned short* sS_, const unsigned short* sW,
                                       int arow, int c, int l16, int quad, float4v acc[4]) {
  const unsigned short* ar = sS_ + (arow + l16) * 72 + quad * 8;
  short8 a0 = *(const short8*)(ar);
  short8 a1 = *(const short8*)(ar + 32);
#pragma unroll
  for (int f = 0; f < 4; ++f) {
    const unsigned short* br = sW + (64 * c + 16 * f + l16) * 72 + quad * 8;
    acc[f] = __builtin_amdgcn_mfma_f32_16x16x32_bf16(a0, *(const short8*)(br), acc[f], 0, 0, 0);
    acc[f] = __builtin_amdgcn_mfma_f32_16x16x32_bf16(a1, *(const short8*)(br + 32), acc[f], 0, 0, 0);
  }
}

__device__ __forceinline__ void wload(const unsigned short* wt, int t, uint4 r[8], int tid) {
  const uint4* g4 = (const uint4*)(wt + t * 16384);
#pragma unroll
  for (int i = 0; i < 8; ++i) r[i] = g4[tid + i * 256];
}

__device__ __forceinline__ void wstore(unsigned short* sWt, const uint4 r[8], int tid) {
#pragma unroll
  for (int i = 0; i < 8; ++i) {
    int cl = tid + i * 256;
    int n = cl >> 4, ch = cl & 15;
    *(uint4*)(&sWt[n * 136 + ch * 8]) = r[i];
  }
}

__device__ __forceinline__ void write_ssp_A(unsigned short* sA_, const float4v v[4],
                                            int arow, int c, int l16, int quad) {
#pragma unroll
  for (int f = 0; f < 4; ++f)
#pragma unroll
    for (int r = 0; r < 4; ++r)
      sA_[(arow + quad * 4 + r) * 136 + 64 * c + 16 * f + l16] = f2bf(sspf(v[f][r]));
}

__global__ __launch_bounds__(256) void mod_kernel(ModArgs A) {
  __shared__ __align__(16) unsigned short sWt[2][128 * 136];
  __shared__ __align__(16) unsigned short sA[2][32 * 136];
  __shared__ __align__(16) unsigned short sG[128 * 72];
  __shared__ __align__(16) unsigned short sS[32 * 72];
  __shared__ float sBias[17 * 128];
  __shared__ float sE[32];

  const int tid  = threadIdx.x;
  const int row0 = blockIdx.x * 32;
  const int lane = tid & 63;
  const int w    = tid >> 6;
  const int g    = w >> 1;
  const int c    = w & 1;
  const int l16  = lane & 15;
  const int quad = lane >> 4;
  const int arow = 16 * g;

  uint4 pf[8];
  wload(A.wt, 0, pf, tid);   // mat 0, earliest issue

  for (int i = tid; i < 17 * 128; i += 256)
    sBias[i] = A.bias[i >> 7][i & 127];
  for (int i = tid; i < 32 * 64; i += 256) {
    int r = i >> 6, k = i & 63;
    sS[r * 72 + k] = f2bf(A.S[(size_t)(row0 + r) * 64 + k]);
  }
  for (int i = tid; i < 32 * 128; i += 256) {
    int r = i >> 7, k = i & 127;
    sA[0][r * 136 + k] = f2bf(sspf(A.feat_in[(size_t)(row0 + r) * 128 + k]));
  }
  {
    const uint4* g4 = (const uint4*)(A.wt + 15 * 16384);
#pragma unroll
    for (int i = 0; i < 4; ++i) {
      int cl = tid + i * 256;
      int n = cl >> 3, ch = cl & 7;
      *(uint4*)(&sG[n * 72 + ch * 8]) = g4[cl];
    }
  }
  if (tid < 32) sE[tid] = 0.0f;

  // per-tile feature registers (for gvec term)
  float4v ff[4];
#pragma unroll
  for (int f = 0; f < 4; ++f) {
    int col = 64 * c + 16 * f + l16;
#pragma unroll
    for (int r = 0; r < 4; ++r)
      ff[f][r] = A.feat_in[(size_t)(row0 + arow + quad * 4 + r) * 128 + col];
  }

  wstore(sWt[0], pf, tid);
  __syncthreads();

  const float4v Z = {0.f, 0.f, 0.f, 0.f};
  float4v fm[4], hs[4], xf[4], t4[4];

  // ---- stage mat0 (W_J) -> fm ; prefetch mat1
  wload(A.wt, 1, pf, tid);
  fm[0] = fm[1] = fm[2] = fm[3] = Z;
  gemm128(sA[0], sWt[0], arow, c, l16, quad, fm);
  wstore(sWt[1], pf, tid);
#pragma unroll
  for (int f = 0; f < 4; ++f) {
    float bb = sBias[0 * 128 + 64 * c + 16 * f + l16];
#pragma unroll
    for (int r = 0; r < 4; ++r) fm[f][r] = sspf(fm[f][r] + bb);
  }
  __syncthreads();

  // ---- stage mat1 (W_I) -> hs ; prefetch mat2 ; gate gemm ; proto -> sA[1]
  wload(A.wt, 2, pf, tid);
  hs[0] = hs[1] = hs[2] = hs[3] = Z;
  gemm128(sA[0], sWt[1], arow, c, l16, quad, hs);
  wstore(sWt[0], pf, tid);
#pragma unroll
  for (int f = 0; f < 4; ++f) {
    float bb = sBias[1 * 128 + 64 * c + 16 * f + l16];
#pragma unroll
    for (int r = 0; r < 4; ++r) hs[f][r] = sspf(hs[f][r] + bb);
  }
  t4[0] = t4[1] = t4[2] = t4[3] = Z;
  gemm64(sS, sG, arow, c, l16, quad, t4);
#pragma unroll
  for (int f = 0; f < 4; ++f)
#pragma unroll
    for (int r = 0; r < 4; ++r) xf[f][r] = fm[f][r] * t4[f][r] + hs[f][r];
  write_ssp_A(sA[1], xf, arow, c, l16, quad);
  __syncthreads();

  int ca = 1;
  // mat m lives in sWt[m&1]; stage m prefetches m+1 into sWt[(m+1)&1]

  // ---- ri residual chain x3 (mats 2..7)
#pragma unroll
  for (int j = 0; j < 3; ++j) {
    const int m1 = 2 + 2 * j, m2 = 3 + 2 * j;
    wload(A.wt, m1 + 1, pf, tid);
    t4[0] = t4[1] = t4[2] = t4[3] = Z;
    gemm128(sA[ca], sWt[m1 & 1], arow, c, l16, quad, t4);
    wstore(sWt[(m1 + 1) & 1], pf, tid);
#pragma unroll
    for (int f = 0; f < 4; ++f) {
      float bb = sBias[m1 * 128 + 64 * c + 16 * f + l16];
#pragma unroll
      for (int r = 0; r < 4; ++r) t4[f][r] += bb;
    }
    write_ssp_A(sA[1 - ca], t4, arow, c, l16, quad);
    __syncthreads();
    ca = 1 - ca;

    wload(A.wt, m2 + 1, pf, tid);
    t4[0] = t4[1] = t4[2] = t4[3] = Z;
    gemm128(sA[ca], sWt[m2 & 1], arow, c, l16, quad, t4);
    wstore(sWt[(m2 + 1) & 1], pf, tid);
#pragma unroll
    for (int f = 0; f < 4; ++f) {
      float bb = sBias[m2 * 128 + 64 * c + 16 * f + l16];
#pragma unroll
      for (int r = 0; r < 4; ++r) xf[f][r] += t4[f][r] + bb;
    }
    write_ssp_A(sA[1 - ca], xf, arow, c, l16, quad);
    __syncthreads();
    ca = 1 - ca;
  }

  // ---- mat8 (W_int): feat2 = feat*gvec + ssp(msg)@W_int + b
  wload(A.wt, 9, pf, tid);
  t4[0] = t4[1] = t4[2] = t4[3] = Z;
  gemm128(sA[ca], sWt[0], arow, c, l16, quad, t4);
  wstore(sWt[1], pf, tid);
#pragma unroll
  for (int f = 0; f < 4; ++f) {
    int col = 64 * c + 16 * f + l16;
    float bb = sBias[8 * 128 + col];
    float gv = sBias[15 * 128 + col];
#pragma unroll
    for (int r = 0; r < 4; ++r) xf[f][r] = ff[f][r] * gv + t4[f][r] + bb;
  }
  write_ssp_A(sA[1 - ca], xf, arow, c, l16, quad);
  __syncthreads();
  ca = 1 - ca;

  // ---- ra residual chain x2 (mats 9..12)
#pragma unroll
  for (int j = 0; j < 2; ++j) {
    const int m1 = 9 + 2 * j, m2 = 10 + 2 * j;
    wload(A.wt, m1 + 1, pf, tid);
    t4[0] = t4[1] = t4[2] = t4[3] = Z;
    gemm128(sA[ca], sWt[m1 & 1], arow, c, l16, quad, t4);
    wstore(sWt[(m1 + 1) & 1], pf, tid);
#pragma unroll
    for (int f = 0; f < 4; ++f) {
      float bb = sBias[m1 * 128 + 64 * c + 16 * f + l16];
#pragma unroll
      for (int r = 0; r < 4; ++r) t4[f][r] += bb;
    }
    write_ssp_A(sA[1 - ca], t4, arow, c, l16, quad);
    __syncthreads();
    ca = 1 - ca;

    wload(A.wt, m2 + 1, pf, tid);
    t4[0] = t4[1] = t4[2] = t4[3] = Z;
    gemm128(sA[ca], sWt[m2 & 1], arow, c, l16, quad, t4);
    wstore(sWt[(m2 + 1) & 1], pf, tid);
#pragma unroll
    for (int f = 0; f < 4; ++f) {
      float bb = sBias[m2 * 128 + 64 * c + 16 * f + l16];
#pragma unroll
      for (int r = 0; r < 4; ++r) xf[f][r] += t4[f][r] + bb;
    }
    write_ssp_A(sA[1 - ca], xf, arow, c, l16, quad);
    __syncthreads();
    ca = 1 - ca;
  }

  // xf is feat2 — write it out now (overlaps with ro chain)
#pragma unroll
  for (int f = 0; f < 4; ++f)
#pragma unroll
    for (int r = 0; r < 4; ++r)
      A.feat_out[(size_t)(row0 + arow + quad * 4 + r) * 128 + 64 * c + 16 * f + l16] = xf[f][r];

  // ---- mat13 (ro_W1) ; prefetch mat14
  wload(A.wt, 14, pf, tid);
  t4[0] = t4[1] = t4[2] = t4[3] = Z;
  gemm128(sA[ca], sWt[1], arow, c, l16, quad, t4);
  wstore(sWt[0], pf, tid);
#pragma unroll
  for (int f = 0; f < 4; ++f) {
    float bb = sBias[13 * 128 + 64 * c + 16 * f + l16];
#pragma unroll
    for (int r = 0; r < 4; ++r) t4[f][r] += bb;
  }
  write_ssp_A(sA[1 - ca], t4, arow, c, l16, quad);
  __syncthreads();
  ca = 1 - ca;

  // ---- mat14 (ro_W2): y = feat2 + ssp(h)@W2 + b ; energy dot
  t4[0] = t4[1] = t4[2] = t4[3] = Z;
  gemm128(sA[ca], sWt[0], arow, c, l16, quad, t4);
  float p0 = 0.f, p1 = 0.f, p2 = 0.f, p3 = 0.f;
#pragma unroll
  for (int f = 0; f < 4; ++f) {
    int col = 64 * c + 16 * f + l16;
    float bb = sBias[14 * 128 + col];
    float wv = sBias[16 * 128 + col];
    p0 += sspf(xf[f][0] + t4[f][0] + bb) * wv;
    p1 += sspf(xf[f][1] + t4[f][1] + bb) * wv;
    p2 += sspf(xf[f][2] + t4[f][2] + bb) * wv;
    p3 += sspf(xf[f][3] + t4[f][3] + bb) * wv;
  }
#pragma unroll
  for (int off = 1; off < 16; off <<= 1) {
    p0 += __shfl_xor(p0, off, 64);
    p1 += __shfl_xor(p1, off, 64);
    p2 += __shfl_xor(p2, off, 64);
    p3 += __shfl_xor(p3, off, 64);
  }
  if (l16 == 0) {
    atomicAdd(&sE[arow + quad * 4 + 0], p0);
    atomicAdd(&sE[arow + quad * 4 + 1], p1);
    atomicAdd(&sE[arow + quad * 4 + 2], p2);
    atomicAdd(&sE[arow + quad * 4 + 3], p3);
  }
  __syncthreads();
  if (tid < 32) {
    float e = sE[tid] + A.b_out[0];
    int row = row0 + tid;
    if (A.first) A.energy[row] = e;
    else         A.energy[row] += e;
  }
}

// ---------------------------------------------------------------------------
extern "C" void kernel_launch(void* const* d_in, const int* in_sizes, int n_in,
                              void* d_out, int out_size, void* d_ws, size_t ws_size,
                              hipStream_t stream) {
  const float* features = (const float*)d_in[1];
  const float* radial   = (const float*)d_in[2];
  const int*   idx12    = (const int*)  d_in[3];
  const float* W_I    = (const float*)d_in[4];
  const float* b_I    = (const float*)d_in[5];
  const float* W_J    = (const float*)d_in[6];
  const float* b_J    = (const float*)d_in[7];
  const float* W_gate = (const float*)d_in[8];
  const float* gvec   = (const float*)d_in[9];
  const float* W_int  = (const float*)d_in[10];
  const float* b_int  = (const float*)d_in[11];
  const float* ri_W1  = (const float*)d_in[12];
  const float* ri_b1  = (const float*)d_in[13];
  const float* ri_W2  = (const float*)d_in[14];
  const float* ri_b2  = (const float*)d_in[15];
  const float* ra_W1  = (const float*)d_in[16];
  const float* ra_b1  = (const float*)d_in[17];
  const float* ra_W2  = (const float*)d_in[18];
  const float* ra_b2  = (const float*)d_in[19];
  const float* ro_W1  = (const float*)d_in[20];
  const float* ro_b1  = (const float*)d_in[21];
  const float* ro_W2  = (const float*)d_in[22];
  const float* ro_b2  = (const float*)d_in[23];
  const float* W_out  = (const float*)d_in[24];
  const float* b_out  = (const float*)d_in[25];

  const int N = in_sizes[1] / 128;   // 8192
  const int P = in_sizes[3] / 2;     // 400000
  const int L = in_sizes[25];        // 5

  // ws layout: S [N*64 f32] | featA [N*128] | featB [N*128] | Wt bf16
  // sort buffers alias featA (only live before the first mod_kernel)
  float* S     = (float*)d_ws;
  float* featA = S + (size_t)N * 64;
  float* featB = featA + (size_t)N * 128;
  unsigned short* Wt = (unsigned short*)(featB + (size_t)N * 128);

  unsigned int* cnt    = (unsigned int*)featA;
  unsigned int* off    = cnt + N;          // N+1 entries
  unsigned int* cur    = off + N + 3;      // keep 16B-ish alignment
  unsigned int* pairid = cur + N;          // 2P entries

  // ---- weight prep
  PrepArgs pa;
  int j = 0;
  for (int l = 0; l < L; ++l) {
    int base = l * MOD_STRIDE;
    const float* fx[15] = {
      W_J + l * 16384, W_I + l * 16384,
      ri_W1 + (l * 3 + 0) * 16384, ri_W2 + (l * 3 + 0) * 16384,
      ri_W1 + (l * 3 + 1) * 16384, ri_W2 + (l * 3 + 1) * 16384,
      ri_W1 + (l * 3 + 2) * 16384, ri_W2 + (l * 3 + 2) * 16384,
      W_int + l * 16384,
      ra_W1 + (l * 2 + 0) * 16384, ra_W2 + (l * 2 + 0) * 16384,
      ra_W1 + (l * 2 + 1) * 16384, ra_W2 + (l * 2 + 1) * 16384,
      ro_W1 + l * 16384, ro_W2 + l * 16384 };
    for (int t = 0; t < 15; ++t) { pa.src[j] = fx[t]; pa.off[j] = base + t * 16384; pa.isgate[j] = 0; ++j; }
    pa.src[j] = W_gate + l * 8192; pa.off[j] = base + 15 * 16384; pa.isgate[j] = 1; ++j;
  }
  pa.nmats = j;
  prep_weights<<<j, 256, 0, stream>>>(pa, Wt);

  // ---- S via counting-sort + gather
  hipMemsetAsync(cnt, 0, (size_t)N * sizeof(unsigned int), stream);
  hist_kernel<<<1024, 256, 0, stream>>>(idx12, cnt, 2 * P);
  scan_kernel<<<1, 256, 0, stream>>>(cnt, off, cur, N);
  place_kernel<<<1024, 256, 0, stream>>>(idx12, cur, pairid, P);
  gather_kernel<<<N, 256, 0, stream>>>(radial, off, pairid, S);

  float* energies   = (float*)d_out;
  float* feat_final = energies + N;

  for (int l = 0; l < L; ++l) {
    ModArgs ma;
    ma.feat_in  = (l == 0) ? features : ((l & 1) ? featA : featB);
    ma.feat_out = (l == L - 1) ? feat_final : ((l & 1) ? featB : featA);
    ma.S  = S;
    ma.wt = Wt + (size_t)l * MOD_STRIDE;
    const float* bias[17] = {
      b_J + l * 128, b_I + l * 128,
      ri_b1 + (l * 3 + 0) * 128, ri_b2 + (l * 3 + 0) * 128,
      ri_b1 + (l * 3 + 1) * 128, ri_b2 + (l * 3 + 1) * 128,
      ri_b1 + (l * 3 + 2) * 128, ri_b2 + (l * 3 + 2) * 128,
      b_int + l * 128,
      ra_b1 + (l * 2 + 0) * 128, ra_b2 + (l * 2 + 0) * 128,
      ra_b1 + (l * 2 + 1) * 128, ra_b2 + (l * 2 + 1) * 128,
      ro_b1 + l * 128, ro_b2 + l * 128,
      gvec + l * 128, W_out + l * 128 };
    for (int q = 0; q < 17; ++q) ma.bias[q] = bias[q];
    ma.b_out  = b_out + l;
    ma.energy = energies;
    ma.first  = (l == 0);
    mod_kernel<<<N / 32, 256, 0, stream>>>(ma);
  }
}

// Round 3
// 469.210 us; speedup vs baseline: 1.2184x; 1.2184x over previous
//
#include <hip/hip_runtime.h>

// ---------------------------------------------------------------------------
// PhysNet stack, MI355X.
//   proto[i] = h_self[i] + fmtab[i] * (S[i] @ W_gate),  S module-invariant.
// Whole 5-module chain is per-atom independent -> ONE fused kernel:
// 80 GEMM stages, weights DMA'd via global_load_lds (swizzled layout),
// activations resident in LDS/regs. S via counting-sort + pipelined gather.
// ---------------------------------------------------------------------------

#define LN2F 0.69314718055994530942f

using short8  = __attribute__((ext_vector_type(8))) short;
using float4v = __attribute__((ext_vector_type(4))) float;
typedef const __attribute__((address_space(1))) unsigned int* gas1_t;
typedef __attribute__((address_space(3))) unsigned int* las3_t;

__device__ __forceinline__ float sspf(float x) {
  float ax = fabsf(x);
  return fmaxf(x, 0.0f) + __logf(1.0f + __expf(-ax)) - LN2F;
}

__device__ __forceinline__ unsigned short f2bf(float x) {
  unsigned int u = __float_as_uint(x);
  u += 0x7fffu + ((u >> 16) & 1u);
  return (unsigned short)(u >> 16);
}

__device__ __forceinline__ void dma16(const void* g, void* l) {
  __builtin_amdgcn_global_load_lds((gas1_t)(unsigned long long)g,
                                   (las3_t)(unsigned long long)l, 16, 0, 0);
}

// block-cooperative 32KB / 16KB DMA: wave-uniform LDS base, lane*16 scatter
__device__ __forceinline__ void dma32k(const unsigned short* g, unsigned short* l,
                                       int w, int lane) {
  const char* gb = (const char*)g + w * 8192 + lane * 16;
  char* lb = (char*)l + w * 8192;
#pragma unroll
  for (int i = 0; i < 8; ++i) dma16(gb + i * 1024, lb + i * 1024);
}
__device__ __forceinline__ void dma16k(const unsigned short* g, unsigned short* l,
                                       int w, int lane) {
  const char* gb = (const char*)g + w * 4096 + lane * 16;
  char* lb = (char*)l + w * 4096;
#pragma unroll
  for (int i = 0; i < 4; ++i) dma16(gb + i * 1024, lb + i * 1024);
}

// ---------------------------------------------------------------------------
// S = segmented sum of radial rows: hist -> scan -> place -> gather
// ---------------------------------------------------------------------------
__global__ __launch_bounds__(256) void hist_kernel(const int* __restrict__ idx,
                                                   unsigned int* __restrict__ cnt, int n2p) {
  int i = blockIdx.x * 256 + threadIdx.x;
  int stride = gridDim.x * 256;
  for (; i < n2p; i += stride) atomicAdd(&cnt[idx[i]], 1u);
}

__global__ __launch_bounds__(256) void scan_kernel(const unsigned int* __restrict__ cnt,
                                                   unsigned int* __restrict__ off,
                                                   unsigned int* __restrict__ cur, int NA) {
  int t = threadIdx.x;
  unsigned int local[32], s = 0;
#pragma unroll
  for (int i = 0; i < 32; ++i) { local[i] = cnt[t * 32 + i]; s += local[i]; }
  unsigned int v = s;
  int lane = t & 63, w = t >> 6;
#pragma unroll
  for (int o = 1; o < 64; o <<= 1) {
    unsigned int u = __shfl_up(v, o, 64);
    if (lane >= o) v += u;
  }
  __shared__ unsigned int wt4[4];
  if (lane == 63) wt4[w] = v;
  __syncthreads();
  unsigned int base = 0;
  for (int k = 0; k < w; ++k) base += wt4[k];
  unsigned int excl = base + v - s;
#pragma unroll
  for (int i = 0; i < 32; ++i) {
    off[t * 32 + i] = excl;
    cur[t * 32 + i] = excl;
    excl += local[i];
  }
  if (t == 255) off[NA] = excl;
}

__global__ __launch_bounds__(256) void place_kernel(const int* __restrict__ idx,
                                                    unsigned int* __restrict__ cur,
                                                    unsigned int* __restrict__ pairid, int P) {
  int i = blockIdx.x * 256 + threadIdx.x;
  int stride = gridDim.x * 256;
  int n2p = 2 * P;
  for (; i < n2p; i += stride) {
    int a = idx[i];
    unsigned int pos = atomicAdd(&cur[a], 1u);
    pairid[pos] = (i >= P) ? (unsigned int)(i - P) : (unsigned int)i;
  }
}

// 8-deep software-pipelined gather (8 radial loads in flight per wave)
__global__ __launch_bounds__(256) void gather_kernel(const float* __restrict__ radial,
                                                     const unsigned int* __restrict__ off,
                                                     const unsigned int* __restrict__ pairid,
                                                     float* __restrict__ S) {
  __shared__ float red[3][64];
  int a = blockIdx.x;
  int lane = threadIdx.x & 63, w = threadIdx.x >> 6;
  unsigned int b = off[a], e = off[a + 1];
  float acc = 0.0f;
  unsigned int j = b + w;
  while (j + 28 < e) {
    unsigned int p[8];
#pragma unroll
    for (int k = 0; k < 8; ++k) p[k] = pairid[j + 4 * k];
#pragma unroll
    for (int k = 0; k < 8; ++k) acc += radial[(size_t)p[k] * 64 + lane];
    j += 32;
  }
  for (; j < e; j += 4) acc += radial[(size_t)pairid[j] * 64 + lane];
  if (w > 0) red[w - 1][lane] = acc;
  __syncthreads();
  if (w == 0) {
    acc += red[0][lane] + red[1][lane] + red[2][lane];
    S[(size_t)a * 64 + lane] = acc;
  }
}

// ---------------------------------------------------------------------------
// Weight prep: fp32 W[k][n] -> bf16, transposed + XOR-swizzled 16B chunks.
// chunk(n,j) at pos = n*16 + (j^(n&15))  (gate: n*8 + (j^(n&7)))
// ---------------------------------------------------------------------------
struct PrepArgs {
  const float* src[80];
  int isgate[80];
};

__global__ __launch_bounds__(256) void prep_weights(PrepArgs A, unsigned short* __restrict__ Wt) {
  int m = blockIdx.x;
  const float* s = A.src[m];
  unsigned short* d = Wt + (size_t)m * 16384;
  if (!A.isgate[m]) {
    for (int it = 0; it < 8; ++it) {
      int q = threadIdx.x + it * 256;
      int n = q & 127, j = q >> 7;
      unsigned short tmp[8];
#pragma unroll
      for (int cc = 0; cc < 8; ++cc) tmp[cc] = f2bf(s[(8 * j + cc) * 128 + n]);
      *(uint4*)(d + (n * 16 + (j ^ (n & 15))) * 8) = *(uint4*)tmp;
    }
  } else {
    for (int it = 0; it < 4; ++it) {
      int q = threadIdx.x + it * 256;
      int n = q & 127, j = q >> 7;
      unsigned short tmp[8];
#pragma unroll
      for (int cc = 0; cc < 8; ++cc) tmp[cc] = f2bf(s[(8 * j + cc) * 128 + n]);
      *(uint4*)(d + (n * 8 + (j ^ (n & 7))) * 8) = *(uint4*)tmp;
    }
  }
}

// bias pack: [l][18][128]: slots 0..14 = stage biases, 15 = gvec, 16 = W_out, 17 = b_out
struct BiasArgs {
  const float* p[17];
  int stride[17];
  const float* b_out;
};

__global__ __launch_bounds__(256) void pack_bias(BiasArgs B, float* __restrict__ dst) {
  int l = blockIdx.x;
  for (int i = threadIdx.x; i < 17 * 128; i += 256) {
    int s = i >> 7;
    dst[(size_t)l * 2304 + i] = B.p[s][l * B.stride[s] + (i & 127)];
  }
  if (threadIdx.x == 0) dst[(size_t)l * 2304 + 17 * 128] = B.b_out[l];
}

// ---------------------------------------------------------------------------
// Fused chain kernel
// ---------------------------------------------------------------------------
struct ChainArgs {
  const float* feat_in;
  const float* S;
  const unsigned short* wt;      // 80 slots x 16384 shorts, consumption order
  const float* bias_pack;        // 5 x 2304 floats
  float* feat_out;               // d_out + N
  float* energy;                 // d_out
  int L;
};

// swizzled-B GEMM, K=128
__device__ __forceinline__ void gemm128s(const unsigned short* sA_, const unsigned short* sW,
                                         int arow, int c, int l16, int quad, float4v acc[4]) {
  const unsigned short* ar = sA_ + (arow + l16) * 136 + quad * 8;
  short8 a0 = *(const short8*)(ar);
  short8 a1 = *(const short8*)(ar + 32);
  short8 a2 = *(const short8*)(ar + 64);
  short8 a3 = *(const short8*)(ar + 96);
#pragma unroll
  for (int f = 0; f < 4; ++f) {
    const unsigned short* bb = sW + (64 * c + 16 * f + l16) * 128;
    acc[f] = __builtin_amdgcn_mfma_f32_16x16x32_bf16(a0, *(const short8*)(bb + ((quad + 0) ^ l16) * 8), acc[f], 0, 0, 0);
    acc[f] = __builtin_amdgcn_mfma_f32_16x16x32_bf16(a1, *(const short8*)(bb + ((quad + 4) ^ l16) * 8), acc[f], 0, 0, 0);
    acc[f] = __builtin_amdgcn_mfma_f32_16x16x32_bf16(a2, *(const short8*)(bb + ((quad + 8) ^ l16) * 8), acc[f], 0, 0, 0);
    acc[f] = __builtin_amdgcn_mfma_f32_16x16x32_bf16(a3, *(const short8*)(bb + ((quad + 12) ^ l16) * 8), acc[f], 0, 0, 0);
  }
}

// swizzled-B gate GEMM, K=64
__device__ __forceinline__ void gemm64s(const unsigned short* sS_, const unsigned short* sW,
                                        int arow, int c, int l16, int quad, float4v acc[4]) {
  const unsigned short* ar = sS_ + (arow + l16) * 72 + quad * 8;
  short8 a0 = *(const short8*)(ar);
  short8 a1 = *(const short8*)(ar + 32);
  int l8 = l16 & 7;
#pragma unroll
  for (int f = 0; f < 4; ++f) {
    const unsigned short* bb = sW + (64 * c + 16 * f + l16) * 64;
    acc[f] = __builtin_amdgcn_mfma_f32_16x16x32_bf16(a0, *(const short8*)(bb + ((quad + 0) ^ l8) * 8), acc[f], 0, 0, 0);
    acc[f] = __builtin_amdgcn_mfma_f32_16x16x32_bf16(a1, *(const short8*)(bb + ((quad + 4) ^ l8) * 8), acc[f], 0, 0, 0);
  }
}

__device__ __forceinline__ void write_ssp_A(unsigned short* sA_, const float4v v[4],
                                            int arow, int c, int l16, int quad) {
#pragma unroll
  for (int f = 0; f < 4; ++f)
#pragma unroll
    for (int r = 0; r < 4; ++r)
      sA_[(arow + quad * 4 + r) * 136 + 64 * c + 16 * f + l16] = f2bf(sspf(v[f][r]));
}

#define Z4(a) { a[0]=Z; a[1]=Z; a[2]=Z; a[3]=Z; }

__global__ __launch_bounds__(256) void chain_kernel(ChainArgs A) {
  __shared__ __align__(16) unsigned short swb[2][16384];   // 64 KB weight dbuf
  __shared__ __align__(16) unsigned short sA[2][32 * 136]; // activation ping-pong
  __shared__ __align__(16) unsigned short sS[32 * 72];
  __shared__ float sBias[2][2304];
  __shared__ float sE[32];

  const int tid  = threadIdx.x;
  const int row0 = blockIdx.x * 32;
  const int lane = tid & 63;
  const int w    = tid >> 6;
  const int g    = w >> 1;
  const int c    = w & 1;
  const int l16  = lane & 15;
  const int quad = lane >> 4;
  const int arow = 16 * g;

  // prologue: DMA gate of module 0 into swb[0]
  dma16k(A.wt, swb[0], w, lane);

  for (int i = tid; i < 32 * 64; i += 256) {
    int r = i >> 6, k = i & 63;
    sS[r * 72 + k] = f2bf(A.S[(size_t)(row0 + r) * 64 + k]);
  }
  for (int i = tid; i < 32 * 128; i += 256) {
    int r = i >> 7, k = i & 127;
    sA[0][r * 136 + k] = f2bf(sspf(A.feat_in[(size_t)(row0 + r) * 128 + k]));
  }
  float4v ff[4];
#pragma unroll
  for (int f = 0; f < 4; ++f) {
    int col = 64 * c + 16 * f + l16;
#pragma unroll
    for (int r = 0; r < 4; ++r)
      ff[f][r] = A.feat_in[(size_t)(row0 + arow + quad * 4 + r) * 128 + col];
  }
  if (tid < 32) sE[tid] = 0.0f;
  __syncthreads();

  const float4v Z = {0.f, 0.f, 0.f, 0.f};
  float4v gG[4], fm[4], xf[4], t4[4];
  float p0 = 0.f, p1 = 0.f, p2 = 0.f, p3 = 0.f, bsum = 0.f;

#pragma unroll 1
  for (int l = 0; l < 5; ++l) {
    const size_t slot0 = (size_t)l * 16 * 16384;
    float* bb = sBias[l & 1];
    const int col0 = 64 * c + l16;

    // ---- t=0: gate GEMM (swb[0]); DMA W_J; stage biases
    dma32k(A.wt + slot0 + 16384, swb[1], w, lane);
    for (int i = tid; i < 2304; i += 256) bb[i] = A.bias_pack[(size_t)l * 2304 + i];
    Z4(gG);
    gemm64s(sS, swb[0], arow, c, l16, quad, gG);
    __syncthreads();

    // ---- t=1: W_J -> fm   (reads sA0, swb1)
    dma32k(A.wt + slot0 + 2 * 16384, swb[0], w, lane);
    Z4(fm);
    gemm128s(sA[0], swb[1], arow, c, l16, quad, fm);
#pragma unroll
    for (int f = 0; f < 4; ++f) {
      float bv = bb[0 * 128 + col0 + 16 * f];
#pragma unroll
      for (int r = 0; r < 4; ++r) fm[f][r] = sspf(fm[f][r] + bv);
    }
    __syncthreads();

    // ---- t=2: W_I -> hs; proto = fm*gG + hs -> sA1
    dma32k(A.wt + slot0 + 3 * 16384, swb[1], w, lane);
    Z4(t4);
    gemm128s(sA[0], swb[0], arow, c, l16, quad, t4);
#pragma unroll
    for (int f = 0; f < 4; ++f) {
      float bv = bb[1 * 128 + col0 + 16 * f];
#pragma unroll
      for (int r = 0; r < 4; ++r) xf[f][r] = fm[f][r] * gG[f][r] + sspf(t4[f][r] + bv);
    }
    write_ssp_A(sA[1], xf, arow, c, l16, quad);
    __syncthreads();

    // ---- t=3..8: ri chain x3 (h: read ca write ca^1 with ssp(t4+b); x: xf update)
#pragma unroll
    for (int jj = 0; jj < 3; ++jj) {
      const int th = 3 + 2 * jj;   // h-stage: reads sA[1], writes sA[0] when jj even...
      // t odd (3,5,7): read sA1 -> write sA0 ; t even (4,6,8): read sA0 -> write sA1
      dma32k(A.wt + slot0 + (size_t)(th + 1) * 16384, swb[th & 1 ? 0 : 1], w, lane);
      Z4(t4);
      gemm128s(sA[1], swb[th & 1], arow, c, l16, quad, t4);
#pragma unroll
      for (int f = 0; f < 4; ++f) {
        float bv = bb[(th - 1) * 128 + col0 + 16 * f];
#pragma unroll
        for (int r = 0; r < 4; ++r) t4[f][r] += bv;
      }
      write_ssp_A(sA[0], t4, arow, c, l16, quad);
      __syncthreads();

      const int tx = th + 1;
      dma32k(A.wt + slot0 + (size_t)(tx + 1) * 16384, swb[tx & 1 ? 0 : 1], w, lane);
      Z4(t4);
      gemm128s(sA[0], swb[tx & 1], arow, c, l16, quad, t4);
#pragma unroll
      for (int f = 0; f < 4; ++f) {
        float bv = bb[(tx - 1) * 128 + col0 + 16 * f];
#pragma unroll
        for (int r = 0; r < 4; ++r) xf[f][r] += t4[f][r] + bv;
      }
      write_ssp_A(sA[1], xf, arow, c, l16, quad);
      __syncthreads();
    }

    // ---- t=9: W_int: xf = ff*gvec + t4 + b  (read sA1/swb1, write sA0)
    dma32k(A.wt + slot0 + 10 * 16384, swb[0], w, lane);
    Z4(t4);
    gemm128s(sA[1], swb[1], arow, c, l16, quad, t4);
#pragma unroll
    for (int f = 0; f < 4; ++f) {
      float bv = bb[8 * 128 + col0 + 16 * f];
      float gv = bb[15 * 128 + col0 + 16 * f];
#pragma unroll
      for (int r = 0; r < 4; ++r) xf[f][r] = ff[f][r] * gv + t4[f][r] + bv;
    }
    write_ssp_A(sA[0], xf, arow, c, l16, quad);
    __syncthreads();

    // ---- t=10..13: ra chain x2
#pragma unroll
    for (int jj = 0; jj < 2; ++jj) {
      const int th = 10 + 2 * jj;  // t even (10,12): read sA0 -> write sA1
      dma32k(A.wt + slot0 + (size_t)(th + 1) * 16384, swb[th & 1 ? 0 : 1], w, lane);
      Z4(t4);
      gemm128s(sA[0], swb[th & 1], arow, c, l16, quad, t4);
#pragma unroll
      for (int f = 0; f < 4; ++f) {
        float bv = bb[(th - 1) * 128 + col0 + 16 * f];
#pragma unroll
        for (int r = 0; r < 4; ++r) t4[f][r] += bv;
      }
      write_ssp_A(sA[1], t4, arow, c, l16, quad);
      __syncthreads();

      const int tx = th + 1;       // t odd (11,13): read sA1 -> write sA0
      dma32k(A.wt + slot0 + (size_t)(tx + 1) * 16384, swb[tx & 1 ? 0 : 1], w, lane);
      Z4(t4);
      gemm128s(sA[1], swb[tx & 1], arow, c, l16, quad, t4);
#pragma unroll
      for (int f = 0; f < 4; ++f) {
        float bv = bb[(tx - 1) * 128 + col0 + 16 * f];
#pragma unroll
        for (int r = 0; r < 4; ++r) xf[f][r] += t4[f][r] + bv;
      }
      write_ssp_A(sA[0], xf, arow, c, l16, quad);
      __syncthreads();
    }

    // xf is feat2; ff for next module
#pragma unroll
    for (int f = 0; f < 4; ++f) ff[f] = xf[f];
    if (l == 4) {
#pragma unroll
      for (int f = 0; f < 4; ++f)
#pragma unroll
        for (int r = 0; r < 4; ++r)
          A.feat_out[(size_t)(row0 + arow + quad * 4 + r) * 128 + 64 * c + 16 * f + l16] = xf[f][r];
    }

    // ---- t=14: ro_W1 (read sA0/swb0, write sA1)
    dma32k(A.wt + slot0 + 15 * 16384, swb[1], w, lane);
    Z4(t4);
    gemm128s(sA[0], swb[0], arow, c, l16, quad, t4);
#pragma unroll
    for (int f = 0; f < 4; ++f) {
      float bv = bb[13 * 128 + col0 + 16 * f];
#pragma unroll
      for (int r = 0; r < 4; ++r) t4[f][r] += bv;
    }
    write_ssp_A(sA[1], t4, arow, c, l16, quad);
    __syncthreads();

    // ---- t=15: ro_W2 (read sA1/swb1); energy; DMA next gate -> swb0
    if (l < 4) dma16k(A.wt + slot0 + 16 * 16384, swb[0], w, lane);
    Z4(t4);
    gemm128s(sA[1], swb[1], arow, c, l16, quad, t4);
#pragma unroll
    for (int f = 0; f < 4; ++f) {
      float bv = bb[14 * 128 + col0 + 16 * f];
      float wv = bb[16 * 128 + col0 + 16 * f];
      p0 += sspf(xf[f][0] + t4[f][0] + bv) * wv;
      p1 += sspf(xf[f][1] + t4[f][1] + bv) * wv;
      p2 += sspf(xf[f][2] + t4[f][2] + bv) * wv;
      p3 += sspf(xf[f][3] + t4[f][3] + bv) * wv;
    }
    bsum += bb[17 * 128];
    __syncthreads();
  }

  // ---- energy reduction
#pragma unroll
  for (int o = 1; o < 16; o <<= 1) {
    p0 += __shfl_xor(p0, o, 64);
    p1 += __shfl_xor(p1, o, 64);
    p2 += __shfl_xor(p2, o, 64);
    p3 += __shfl_xor(p3, o, 64);
  }
  if (l16 == 0) {
    atomicAdd(&sE[arow + quad * 4 + 0], p0);
    atomicAdd(&sE[arow + quad * 4 + 1], p1);
    atomicAdd(&sE[arow + quad * 4 + 2], p2);
    atomicAdd(&sE[arow + quad * 4 + 3], p3);
  }
  __syncthreads();
  if (tid < 32) A.energy[row0 + tid] = sE[tid] + bsum;
}

// ---------------------------------------------------------------------------
extern "C" void kernel_launch(void* const* d_in, const int* in_sizes, int n_in,
                              void* d_out, int out_size, void* d_ws, size_t ws_size,
                              hipStream_t stream) {
  const float* features = (const float*)d_in[1];
  const float* radial   = (const float*)d_in[2];
  const int*   idx12    = (const int*)  d_in[3];
  const float* W_I    = (const float*)d_in[4];
  const float* b_I    = (const float*)d_in[5];
  const float* W_J    = (const float*)d_in[6];
  const float* b_J    = (const float*)d_in[7];
  const float* W_gate = (const float*)d_in[8];
  const float* gvec   = (const float*)d_in[9];
  const float* W_int  = (const float*)d_in[10];
  const float* b_int  = (const float*)d_in[11];
  const float* ri_W1  = (const float*)d_in[12];
  const float* ri_b1  = (const float*)d_in[13];
  const float* ri_W2  = (const float*)d_in[14];
  const float* ri_b2  = (const float*)d_in[15];
  const float* ra_W1  = (const float*)d_in[16];
  const float* ra_b1  = (const float*)d_in[17];
  const float* ra_W2  = (const float*)d_in[18];
  const float* ra_b2  = (const float*)d_in[19];
  const float* ro_W1  = (const float*)d_in[20];
  const float* ro_b1  = (const float*)d_in[21];
  const float* ro_W2  = (const float*)d_in[22];
  const float* ro_b2  = (const float*)d_in[23];
  const float* W_out  = (const float*)d_in[24];
  const float* b_out  = (const float*)d_in[25];

  const int N = in_sizes[1] / 128;   // 8192
  const int P = in_sizes[3] / 2;     // 400000
  const int L = in_sizes[25];        // 5

  // ws layout: S | bias_pack | Wt | cnt | off | cur | pairid
  float* S = (float*)d_ws;
  float* bias_pack = S + (size_t)N * 64;
  unsigned short* Wt = (unsigned short*)(bias_pack + 5 * 2304);
  unsigned int* cnt    = (unsigned int*)(Wt + (size_t)80 * 16384);
  unsigned int* off    = cnt + N;
  unsigned int* cur    = off + N + 3;
  unsigned int* pairid = cur + N;

  // ---- weight prep (swizzled, consumption order: gate,WJ,WI,ri*6,Wint,ra*4,ro*2)
  PrepArgs pa;
  for (int l = 0; l < L; ++l) {
    const float* fx[16] = {
      W_gate + l * 8192,
      W_J + l * 16384, W_I + l * 16384,
      ri_W1 + (l * 3 + 0) * 16384, ri_W2 + (l * 3 + 0) * 16384,
      ri_W1 + (l * 3 + 1) * 16384, ri_W2 + (l * 3 + 1) * 16384,
      ri_W1 + (l * 3 + 2) * 16384, ri_W2 + (l * 3 + 2) * 16384,
      W_int + l * 16384,
      ra_W1 + (l * 2 + 0) * 16384, ra_W2 + (l * 2 + 0) * 16384,
      ra_W1 + (l * 2 + 1) * 16384, ra_W2 + (l * 2 + 1) * 16384,
      ro_W1 + l * 16384, ro_W2 + l * 16384 };
    for (int t = 0; t < 16; ++t) { pa.src[l * 16 + t] = fx[t]; pa.isgate[l * 16 + t] = (t == 0); }
  }
  prep_weights<<<80, 256, 0, stream>>>(pa, Wt);

  BiasArgs ba;
  const float* bp[17] = { b_J, b_I,
    ri_b1, ri_b2, ri_b1 + 128, ri_b2 + 128, ri_b1 + 256, ri_b2 + 256,
    b_int, ra_b1, ra_b2, ra_b1 + 128, ra_b2 + 128, ro_b1, ro_b2, gvec, W_out };
  int st[17] = {128,128, 384,384,384,384,384,384, 128, 256,256,256,256, 128,128,128,128};
  for (int q = 0; q < 17; ++q) { ba.p[q] = bp[q]; ba.stride[q] = st[q]; }
  ba.b_out = b_out;
  pack_bias<<<5, 256, 0, stream>>>(ba, bias_pack);

  // ---- S via counting-sort + gather
  hipMemsetAsync(cnt, 0, (size_t)N * sizeof(unsigned int), stream);
  hist_kernel<<<1024, 256, 0, stream>>>(idx12, cnt, 2 * P);
  scan_kernel<<<1, 256, 0, stream>>>(cnt, off, cur, N);
  place_kernel<<<1024, 256, 0, stream>>>(idx12, cur, pairid, P);
  gather_kernel<<<N, 256, 0, stream>>>(radial, off, pairid, S);

  // ---- fused 5-module chain
  ChainArgs ca;
  ca.feat_in   = features;
  ca.S         = S;
  ca.wt        = Wt;
  ca.bias_pack = bias_pack;
  ca.energy    = (float*)d_out;
  ca.feat_out  = (float*)d_out + N;
  ca.L         = L;
  chain_kernel<<<N / 32, 256, 0, stream>>>(ca);
}

// Round 4
// 369.236 us; speedup vs baseline: 1.5483x; 1.2708x over previous
//
#include <hip/hip_runtime.h>

// ---------------------------------------------------------------------------
// PhysNet stack, MI355X.
//   proto[i] = h_self[i] + fmtab[i] * (S[i] @ W_gate),  S module-invariant.
// ONE fused chain kernel (80 GEMM stages, 8 waves/block for ILP), weights
// DMA'd via global_load_lds (swizzled). S via LDS-histogram radix sort
// (no global atomics) + pipelined gather.
// ---------------------------------------------------------------------------

#define LN2F 0.69314718055994530942f
#define NB 128   // sort blocks

using short8  = __attribute__((ext_vector_type(8))) short;
using float4v = __attribute__((ext_vector_type(4))) float;
typedef const __attribute__((address_space(1))) unsigned int* gas1_t;
typedef __attribute__((address_space(3))) unsigned int* las3_t;

__device__ __forceinline__ float sspf(float x) {
  float ax = fabsf(x);
  return fmaxf(x, 0.0f) + __logf(1.0f + __expf(-ax)) - LN2F;
}

__device__ __forceinline__ unsigned short f2bf(float x) {
  unsigned int u = __float_as_uint(x);
  u += 0x7fffu + ((u >> 16) & 1u);
  return (unsigned short)(u >> 16);
}

__device__ __forceinline__ void dma16(const void* g, void* l) {
  __builtin_amdgcn_global_load_lds((gas1_t)(unsigned long long)g,
                                   (las3_t)(unsigned long long)l, 16, 0, 0);
}

// 8-wave block DMA: 32KB -> 4KB/wave, 16KB -> 2KB/wave
__device__ __forceinline__ void dma32k(const unsigned short* g, unsigned short* l,
                                       int w, int lane) {
  const char* gb = (const char*)g + w * 4096 + lane * 16;
  char* lb = (char*)l + w * 4096;
#pragma unroll
  for (int i = 0; i < 4; ++i) dma16(gb + i * 1024, lb + i * 1024);
}
__device__ __forceinline__ void dma16k(const unsigned short* g, unsigned short* l,
                                       int w, int lane) {
  const char* gb = (const char*)g + w * 2048 + lane * 16;
  char* lb = (char*)l + w * 2048;
#pragma unroll
  for (int i = 0; i < 2; ++i) dma16(gb + i * 1024, lb + i * 1024);
}

// ---------------------------------------------------------------------------
// S-path: LDS-hist radix sort (no global atomics) + gather
// ---------------------------------------------------------------------------
__global__ __launch_bounds__(256) void hist_pass(const int* __restrict__ idx,
                                                 unsigned int* __restrict__ H,
                                                 int n2p, int C) {
  __shared__ unsigned int h[8192];
  int b = blockIdx.x, tid = threadIdx.x;
  for (int i = tid; i < 8192; i += 256) h[i] = 0;
  __syncthreads();
  int s = b * C, e = min(s + C, n2p);
  for (int i = s + tid; i < e; i += 256) atomicAdd(&h[idx[i]], 1u);
  __syncthreads();
  for (int i = tid; i < 8192; i += 256) H[(size_t)b * 8192 + i] = h[i];
}

// per-bin exclusive scan over blocks (in place) + column totals
__global__ __launch_bounds__(256) void col_scan(unsigned int* __restrict__ H,
                                                unsigned int* __restrict__ tot) {
  int a = blockIdx.x * 256 + threadIdx.x;   // 32 blocks x 256 = 8192 bins
  unsigned int run = 0;
  for (int b = 0; b < NB; ++b) {
    unsigned int v = H[(size_t)b * 8192 + a];
    H[(size_t)b * 8192 + a] = run;
    run += v;
  }
  tot[a] = run;
}

__global__ __launch_bounds__(256) void scan_kernel(const unsigned int* __restrict__ cnt,
                                                   unsigned int* __restrict__ off, int NA) {
  int t = threadIdx.x;
  unsigned int local[32], s = 0;
#pragma unroll
  for (int i = 0; i < 32; ++i) { local[i] = cnt[t * 32 + i]; s += local[i]; }
  unsigned int v = s;
  int lane = t & 63, w = t >> 6;
#pragma unroll
  for (int o = 1; o < 64; o <<= 1) {
    unsigned int u = __shfl_up(v, o, 64);
    if (lane >= o) v += u;
  }
  __shared__ unsigned int wt4[4];
  if (lane == 63) wt4[w] = v;
  __syncthreads();
  unsigned int base = 0;
  for (int k = 0; k < w; ++k) base += wt4[k];
  unsigned int excl = base + v - s;
#pragma unroll
  for (int i = 0; i < 32; ++i) { off[t * 32 + i] = excl; excl += local[i]; }
  if (t == 255) off[NA] = excl;
}

__global__ __launch_bounds__(256) void place_pass(const int* __restrict__ idx,
                                                  const unsigned int* __restrict__ H,
                                                  const unsigned int* __restrict__ off,
                                                  unsigned int* __restrict__ pairid,
                                                  int P, int C) {
  __shared__ unsigned int pos[8192];
  int b = blockIdx.x, tid = threadIdx.x;
  for (int i = tid; i < 8192; i += 256)
    pos[i] = off[i] + H[(size_t)b * 8192 + i];
  __syncthreads();
  int n2p = 2 * P;
  int s = b * C, e = min(s + C, n2p);
  for (int i = s + tid; i < e; i += 256) {
    int a = idx[i];
    unsigned int p = atomicAdd(&pos[a], 1u);
    pairid[p] = (i >= P) ? (unsigned int)(i - P) : (unsigned int)i;
  }
}

// 8-deep software-pipelined gather
__global__ __launch_bounds__(256) void gather_kernel(const float* __restrict__ radial,
                                                     const unsigned int* __restrict__ off,
                                                     const unsigned int* __restrict__ pairid,
                                                     float* __restrict__ S) {
  __shared__ float red[3][64];
  int a = blockIdx.x;
  int lane = threadIdx.x & 63, w = threadIdx.x >> 6;
  unsigned int b = off[a], e = off[a + 1];
  float acc = 0.0f;
  unsigned int j = b + w;
  while (j + 28 < e) {
    unsigned int p[8];
#pragma unroll
    for (int k = 0; k < 8; ++k) p[k] = pairid[j + 4 * k];
#pragma unroll
    for (int k = 0; k < 8; ++k) acc += radial[(size_t)p[k] * 64 + lane];
    j += 32;
  }
  for (; j < e; j += 4) acc += radial[(size_t)pairid[j] * 64 + lane];
  if (w > 0) red[w - 1][lane] = acc;
  __syncthreads();
  if (w == 0) {
    acc += red[0][lane] + red[1][lane] + red[2][lane];
    S[(size_t)a * 64 + lane] = acc;
  }
}

// ---------------------------------------------------------------------------
// Weight prep: fp32 W[k][n] -> bf16, transposed + XOR-swizzled 16B chunks.
// chunk(n,j) at pos = n*16 + (j^(n&15))  (gate: n*8 + (j^(n&7)))
// ---------------------------------------------------------------------------
struct PrepArgs {
  const float* src[80];
  int isgate[80];
};

__global__ __launch_bounds__(256) void prep_weights(PrepArgs A, unsigned short* __restrict__ Wt) {
  int m = blockIdx.x;
  const float* s = A.src[m];
  unsigned short* d = Wt + (size_t)m * 16384;
  if (!A.isgate[m]) {
    for (int it = 0; it < 8; ++it) {
      int q = threadIdx.x + it * 256;
      int n = q & 127, j = q >> 7;
      unsigned short tmp[8];
#pragma unroll
      for (int cc = 0; cc < 8; ++cc) tmp[cc] = f2bf(s[(8 * j + cc) * 128 + n]);
      *(uint4*)(d + (n * 16 + (j ^ (n & 15))) * 8) = *(uint4*)tmp;
    }
  } else {
    for (int it = 0; it < 4; ++it) {
      int q = threadIdx.x + it * 256;
      int n = q & 127, j = q >> 7;
      unsigned short tmp[8];
#pragma unroll
      for (int cc = 0; cc < 8; ++cc) tmp[cc] = f2bf(s[(8 * j + cc) * 128 + n]);
      *(uint4*)(d + (n * 8 + (j ^ (n & 7))) * 8) = *(uint4*)tmp;
    }
  }
}

struct BiasArgs {
  const float* p[17];
  int stride[17];
  const float* b_out;
};

__global__ __launch_bounds__(256) void pack_bias(BiasArgs B, float* __restrict__ dst) {
  int l = blockIdx.x;
  for (int i = threadIdx.x; i < 17 * 128; i += 256) {
    int s = i >> 7;
    dst[(size_t)l * 2304 + i] = B.p[s][l * B.stride[s] + (i & 127)];
  }
  if (threadIdx.x == 0) dst[(size_t)l * 2304 + 17 * 128] = B.b_out[l];
}

// ---------------------------------------------------------------------------
// Fused chain kernel: 512 threads = 8 waves; wave (g,c): rows 16g..16g+15,
// cols 32c..32c+31.
// ---------------------------------------------------------------------------
struct ChainArgs {
  const float* feat_in;
  const float* S;
  const unsigned short* wt;      // 80 slots x 16384 shorts
  const float* bias_pack;        // 5 x 2304 floats
  float* feat_out;
  float* energy;
};

__device__ __forceinline__ void gemm128s(const unsigned short* sA_, const unsigned short* sW,
                                         int arow, int c, int l16, int quad, float4v acc[2]) {
  const unsigned short* ar = sA_ + (arow + l16) * 136 + quad * 8;
  short8 a0 = *(const short8*)(ar);
  short8 a1 = *(const short8*)(ar + 32);
  short8 a2 = *(const short8*)(ar + 64);
  short8 a3 = *(const short8*)(ar + 96);
#pragma unroll
  for (int f = 0; f < 2; ++f) {
    const unsigned short* bb = sW + (32 * c + 16 * f + l16) * 128;
    acc[f] = __builtin_amdgcn_mfma_f32_16x16x32_bf16(a0, *(const short8*)(bb + ((quad + 0) ^ l16) * 8), acc[f], 0, 0, 0);
    acc[f] = __builtin_amdgcn_mfma_f32_16x16x32_bf16(a1, *(const short8*)(bb + ((quad + 4) ^ l16) * 8), acc[f], 0, 0, 0);
    acc[f] = __builtin_amdgcn_mfma_f32_16x16x32_bf16(a2, *(const short8*)(bb + ((quad + 8) ^ l16) * 8), acc[f], 0, 0, 0);
    acc[f] = __builtin_amdgcn_mfma_f32_16x16x32_bf16(a3, *(const short8*)(bb + ((quad + 12) ^ l16) * 8), acc[f], 0, 0, 0);
  }
}

__device__ __forceinline__ void gemm64s(const unsigned short* sS_, const unsigned short* sW,
                                        int arow, int c, int l16, int quad, float4v acc[2]) {
  const unsigned short* ar = sS_ + (arow + l16) * 72 + quad * 8;
  short8 a0 = *(const short8*)(ar);
  short8 a1 = *(const short8*)(ar + 32);
  int l8 = l16 & 7;
#pragma unroll
  for (int f = 0; f < 2; ++f) {
    const unsigned short* bb = sW + (32 * c + 16 * f + l16) * 64;
    acc[f] = __builtin_amdgcn_mfma_f32_16x16x32_bf16(a0, *(const short8*)(bb + ((quad + 0) ^ l8) * 8), acc[f], 0, 0, 0);
    acc[f] = __builtin_amdgcn_mfma_f32_16x16x32_bf16(a1, *(const short8*)(bb + ((quad + 4) ^ l8) * 8), acc[f], 0, 0, 0);
  }
}

__device__ __forceinline__ void write_ssp_A(unsigned short* sA_, const float4v v[2],
                                            int arow, int c, int l16, int quad) {
#pragma unroll
  for (int f = 0; f < 2; ++f)
#pragma unroll
    for (int r = 0; r < 4; ++r)
      sA_[(arow + quad * 4 + r) * 136 + 32 * c + 16 * f + l16] = f2bf(sspf(v[f][r]));
}

#define Z2(a) { a[0]=Z; a[1]=Z; }

__global__ __launch_bounds__(512) void chain_kernel(ChainArgs A) {
  __shared__ __align__(16) unsigned short swb[2][16384];   // 64 KB weight dbuf
  __shared__ __align__(16) unsigned short sA[2][32 * 136];
  __shared__ __align__(16) unsigned short sS[32 * 72];
  __shared__ float sBias[2304];
  __shared__ float sE[32];

  const int tid  = threadIdx.x;
  const int row0 = blockIdx.x * 32;
  const int lane = tid & 63;
  const int w    = tid >> 6;       // 0..7
  const int g    = w >> 2;         // row group 0..1
  const int c    = w & 3;          // col quarter 0..3
  const int l16  = lane & 15;
  const int quad = lane >> 4;
  const int arow = 16 * g;
  const int col0 = 32 * c + l16;

  dma16k(A.wt, swb[0], w, lane);   // module-0 gate

  for (int i = tid; i < 32 * 64; i += 512) {
    int r = i >> 6, k = i & 63;
    sS[r * 72 + k] = f2bf(A.S[(size_t)(row0 + r) * 64 + k]);
  }
  for (int i = tid; i < 32 * 128; i += 512) {
    int r = i >> 7, k = i & 127;
    sA[0][r * 136 + k] = f2bf(sspf(A.feat_in[(size_t)(row0 + r) * 128 + k]));
  }
  float4v ff[2];
#pragma unroll
  for (int f = 0; f < 2; ++f)
#pragma unroll
    for (int r = 0; r < 4; ++r)
      ff[f][r] = A.feat_in[(size_t)(row0 + arow + quad * 4 + r) * 128 + col0 + 16 * f];
  if (tid < 32) sE[tid] = 0.0f;
  __syncthreads();

  const float4v Z = {0.f, 0.f, 0.f, 0.f};
  float4v gG[2], fm[2], xf[2], t4[2];
  float p0 = 0.f, p1 = 0.f, p2 = 0.f, p3 = 0.f, bsum = 0.f;

#pragma unroll 1
  for (int l = 0; l < 5; ++l) {
    const size_t slot0 = (size_t)l * 16 * 16384;

    // ---- t=0: gate GEMM; DMA W_J; stage biases
    dma32k(A.wt + slot0 + 16384, swb[1], w, lane);
    for (int i = tid; i < 2304; i += 512) sBias[i] = A.bias_pack[(size_t)l * 2304 + i];
    Z2(gG);
    gemm64s(sS, swb[0], arow, c, l16, quad, gG);
    __syncthreads();

    // ---- t=1: W_J -> fm
    dma32k(A.wt + slot0 + 2 * 16384, swb[0], w, lane);
    Z2(fm);
    gemm128s(sA[0], swb[1], arow, c, l16, quad, fm);
#pragma unroll
    for (int f = 0; f < 2; ++f) {
      float bv = sBias[0 * 128 + col0 + 16 * f];
#pragma unroll
      for (int r = 0; r < 4; ++r) fm[f][r] = sspf(fm[f][r] + bv);
    }
    __syncthreads();

    // ---- t=2: W_I; proto = fm*gG + ssp(t4+b) -> sA1
    dma32k(A.wt + slot0 + 3 * 16384, swb[1], w, lane);
    Z2(t4);
    gemm128s(sA[0], swb[0], arow, c, l16, quad, t4);
#pragma unroll
    for (int f = 0; f < 2; ++f) {
      float bv = sBias[1 * 128 + col0 + 16 * f];
#pragma unroll
      for (int r = 0; r < 4; ++r) xf[f][r] = fm[f][r] * gG[f][r] + sspf(t4[f][r] + bv);
    }
    write_ssp_A(sA[1], xf, arow, c, l16, quad);
    __syncthreads();

    // ---- t=3..8: ri chain x3
#pragma unroll
    for (int jj = 0; jj < 3; ++jj) {
      const int th = 3 + 2 * jj;
      dma32k(A.wt + slot0 + (size_t)(th + 1) * 16384, swb[th & 1 ? 0 : 1], w, lane);
      Z2(t4);
      gemm128s(sA[1], swb[th & 1], arow, c, l16, quad, t4);
#pragma unroll
      for (int f = 0; f < 2; ++f) {
        float bv = sBias[(th - 1) * 128 + col0 + 16 * f];
#pragma unroll
        for (int r = 0; r < 4; ++r) t4[f][r] += bv;
      }
      write_ssp_A(sA[0], t4, arow, c, l16, quad);
      __syncthreads();

      const int tx = th + 1;
      dma32k(A.wt + slot0 + (size_t)(tx + 1) * 16384, swb[tx & 1 ? 0 : 1], w, lane);
      Z2(t4);
      gemm128s(sA[0], swb[tx & 1], arow, c, l16, quad, t4);
#pragma unroll
      for (int f = 0; f < 2; ++f) {
        float bv = sBias[(tx - 1) * 128 + col0 + 16 * f];
#pragma unroll
        for (int r = 0; r < 4; ++r) xf[f][r] += t4[f][r] + bv;
      }
      write_ssp_A(sA[1], xf, arow, c, l16, quad);
      __syncthreads();
    }

    // ---- t=9: W_int: xf = ff*gvec + t4 + b  (read sA1/swb1, write sA0)
    dma32k(A.wt + slot0 + 10 * 16384, swb[0], w, lane);
    Z2(t4);
    gemm128s(sA[1], swb[1], arow, c, l16, quad, t4);
#pragma unroll
    for (int f = 0; f < 2; ++f) {
      float bv = sBias[8 * 128 + col0 + 16 * f];
      float gv = sBias[15 * 128 + col0 + 16 * f];
#pragma unroll
      for (int r = 0; r < 4; ++r) xf[f][r] = ff[f][r] * gv + t4[f][r] + bv;
    }
    write_ssp_A(sA[0], xf, arow, c, l16, quad);
    __syncthreads();

    // ---- t=10..13: ra chain x2
#pragma unroll
    for (int jj = 0; jj < 2; ++jj) {
      const int th = 10 + 2 * jj;
      dma32k(A.wt + slot0 + (size_t)(th + 1) * 16384, swb[th & 1 ? 0 : 1], w, lane);
      Z2(t4);
      gemm128s(sA[0], swb[th & 1], arow, c, l16, quad, t4);
#pragma unroll
      for (int f = 0; f < 2; ++f) {
        float bv = sBias[(th - 1) * 128 + col0 + 16 * f];
#pragma unroll
        for (int r = 0; r < 4; ++r) t4[f][r] += bv;
      }
      write_ssp_A(sA[1], t4, arow, c, l16, quad);
      __syncthreads();

      const int tx = th + 1;
      dma32k(A.wt + slot0 + (size_t)(tx + 1) * 16384, swb[tx & 1 ? 0 : 1], w, lane);
      Z2(t4);
      gemm128s(sA[1], swb[tx & 1], arow, c, l16, quad, t4);
#pragma unroll
      for (int f = 0; f < 2; ++f) {
        float bv = sBias[(tx - 1) * 128 + col0 + 16 * f];
#pragma unroll
        for (int r = 0; r < 4; ++r) xf[f][r] += t4[f][r] + bv;
      }
      write_ssp_A(sA[0], xf, arow, c, l16, quad);
      __syncthreads();
    }

    // xf is feat2
#pragma unroll
    for (int f = 0; f < 2; ++f) ff[f] = xf[f];
    if (l == 4) {
#pragma unroll
      for (int f = 0; f < 2; ++f)
#pragma unroll
        for (int r = 0; r < 4; ++r)
          A.feat_out[(size_t)(row0 + arow + quad * 4 + r) * 128 + col0 + 16 * f] = xf[f][r];
    }

    // ---- t=14: ro_W1 (read sA0/swb0, write sA1)
    dma32k(A.wt + slot0 + 15 * 16384, swb[1], w, lane);
    Z2(t4);
    gemm128s(sA[0], swb[0], arow, c, l16, quad, t4);
#pragma unroll
    for (int f = 0; f < 2; ++f) {
      float bv = sBias[13 * 128 + col0 + 16 * f];
#pragma unroll
      for (int r = 0; r < 4; ++r) t4[f][r] += bv;
    }
    write_ssp_A(sA[1], t4, arow, c, l16, quad);
    __syncthreads();

    // ---- t=15: ro_W2; energy; DMA next gate -> swb0
    if (l < 4) dma16k(A.wt + slot0 + 16 * 16384, swb[0], w, lane);
    Z2(t4);
    gemm128s(sA[1], swb[1], arow, c, l16, quad, t4);
#pragma unroll
    for (int f = 0; f < 2; ++f) {
      float bv = sBias[14 * 128 + col0 + 16 * f];
      float wv = sBias[16 * 128 + col0 + 16 * f];
      p0 += sspf(xf[f][0] + t4[f][0] + bv) * wv;
      p1 += sspf(xf[f][1] + t4[f][1] + bv) * wv;
      p2 += sspf(xf[f][2] + t4[f][2] + bv) * wv;
      p3 += sspf(xf[f][3] + t4[f][3] + bv) * wv;
    }
    bsum += sBias[17 * 128];
    __syncthreads();
  }

  // ---- energy reduction
#pragma unroll
  for (int o = 1; o < 16; o <<= 1) {
    p0 += __shfl_xor(p0, o, 64);
    p1 += __shfl_xor(p1, o, 64);
    p2 += __shfl_xor(p2, o, 64);
    p3 += __shfl_xor(p3, o, 64);
  }
  if (l16 == 0) {
    atomicAdd(&sE[arow + quad * 4 + 0], p0);
    atomicAdd(&sE[arow + quad * 4 + 1], p1);
    atomicAdd(&sE[arow + quad * 4 + 2], p2);
    atomicAdd(&sE[arow + quad * 4 + 3], p3);
  }
  __syncthreads();
  if (tid < 32) A.energy[row0 + tid] = sE[tid] + bsum;
}

// ---------------------------------------------------------------------------
extern "C" void kernel_launch(void* const* d_in, const int* in_sizes, int n_in,
                              void* d_out, int out_size, void* d_ws, size_t ws_size,
                              hipStream_t stream) {
  const float* features = (const float*)d_in[1];
  const float* radial   = (const float*)d_in[2];
  const int*   idx12    = (const int*)  d_in[3];
  const float* W_I    = (const float*)d_in[4];
  const float* b_I    = (const float*)d_in[5];
  const float* W_J    = (const float*)d_in[6];
  const float* b_J    = (const float*)d_in[7];
  const float* W_gate = (const float*)d_in[8];
  const float* gvec   = (const float*)d_in[9];
  const float* W_int  = (const float*)d_in[10];
  const float* b_int  = (const float*)d_in[11];
  const float* ri_W1  = (const float*)d_in[12];
  const float* ri_b1  = (const float*)d_in[13];
  const float* ri_W2  = (const float*)d_in[14];
  const float* ri_b2  = (const float*)d_in[15];
  const float* ra_W1  = (const float*)d_in[16];
  const float* ra_b1  = (const float*)d_in[17];
  const float* ra_W2  = (const float*)d_in[18];
  const float* ra_b2  = (const float*)d_in[19];
  const float* ro_W1  = (const float*)d_in[20];
  const float* ro_b1  = (const float*)d_in[21];
  const float* ro_W2  = (const float*)d_in[22];
  const float* ro_b2  = (const float*)d_in[23];
  const float* W_out  = (const float*)d_in[24];
  const float* b_out  = (const float*)d_in[25];

  const int N = in_sizes[1] / 128;   // 8192
  const int P = in_sizes[3] / 2;     // 400000
  const int L = in_sizes[25];        // 5
  const int n2p = 2 * P;
  const int C = (n2p + NB - 1) / NB;

  // ws layout: S | bias_pack | Wt | H | tot | off | pairid  (~12 MB)
  float* S = (float*)d_ws;
  float* bias_pack = S + (size_t)N * 64;
  unsigned short* Wt = (unsigned short*)(bias_pack + 5 * 2304);
  unsigned int* H      = (unsigned int*)(Wt + (size_t)80 * 16384);
  unsigned int* tot    = H + (size_t)NB * 8192;
  unsigned int* off    = tot + N;
  unsigned int* pairid = off + N + 4;

  // ---- weight prep (consumption order: gate,WJ,WI,ri*6,Wint,ra*4,ro*2)
  PrepArgs pa;
  for (int l = 0; l < L; ++l) {
    const float* fx[16] = {
      W_gate + l * 8192,
      W_J + l * 16384, W_I + l * 16384,
      ri_W1 + (l * 3 + 0) * 16384, ri_W2 + (l * 3 + 0) * 16384,
      ri_W1 + (l * 3 + 1) * 16384, ri_W2 + (l * 3 + 1) * 16384,
      ri_W1 + (l * 3 + 2) * 16384, ri_W2 + (l * 3 + 2) * 16384,
      W_int + l * 16384,
      ra_W1 + (l * 2 + 0) * 16384, ra_W2 + (l * 2 + 0) * 16384,
      ra_W1 + (l * 2 + 1) * 16384, ra_W2 + (l * 2 + 1) * 16384,
      ro_W1 + l * 16384, ro_W2 + l * 16384 };
    for (int t = 0; t < 16; ++t) { pa.src[l * 16 + t] = fx[t]; pa.isgate[l * 16 + t] = (t == 0); }
  }
  prep_weights<<<80, 256, 0, stream>>>(pa, Wt);

  BiasArgs ba;
  const float* bp[17] = { b_J, b_I,
    ri_b1, ri_b2, ri_b1 + 128, ri_b2 + 128, ri_b1 + 256, ri_b2 + 256,
    b_int, ra_b1, ra_b2, ra_b1 + 128, ra_b2 + 128, ro_b1, ro_b2, gvec, W_out };
  int st[17] = {128,128, 384,384,384,384,384,384, 128, 256,256,256,256, 128,128,128,128};
  for (int q = 0; q < 17; ++q) { ba.p[q] = bp[q]; ba.stride[q] = st[q]; }
  ba.b_out = b_out;
  pack_bias<<<5, 256, 0, stream>>>(ba, bias_pack);

  // ---- S via LDS-hist sort + gather (no global atomics)
  hist_pass<<<NB, 256, 0, stream>>>(idx12, H, n2p, C);
  col_scan<<<32, 256, 0, stream>>>(H, tot);
  scan_kernel<<<1, 256, 0, stream>>>(tot, off, N);
  place_pass<<<NB, 256, 0, stream>>>(idx12, H, off, pairid, P, C);
  gather_kernel<<<N, 256, 0, stream>>>(radial, off, pairid, S);

  // ---- fused 5-module chain
  ChainArgs ca;
  ca.feat_in   = features;
  ca.S         = S;
  ca.wt        = Wt;
  ca.bias_pack = bias_pack;
  ca.energy    = (float*)d_out;
  ca.feat_out  = (float*)d_out + N;
  chain_kernel<<<N / 32, 512, 0, stream>>>(ca);
}

// Round 5
// 349.469 us; speedup vs baseline: 1.6359x; 1.0566x over previous
//
#include <hip/hip_runtime.h>

// ---------------------------------------------------------------------------
// PhysNet stack, MI355X.
//   proto[i] = h_self[i] + fmtab[i] * (S[i] @ W_gate),  S module-invariant.
// ONE fused chain kernel (80 GEMM stages, 16 waves/block = 4 waves/SIMD),
// weights DMA'd via global_load_lds (swizzled). S via LDS-histogram radix
// sort (no global atomics) + fully-predicated pipelined gather.
// ---------------------------------------------------------------------------

#define LN2F 0.69314718055994530942f
#define NB 128   // sort blocks

using short8  = __attribute__((ext_vector_type(8))) short;
using float4v = __attribute__((ext_vector_type(4))) float;
typedef const __attribute__((address_space(1))) unsigned int* gas1_t;
typedef __attribute__((address_space(3))) unsigned int* las3_t;

__device__ __forceinline__ float sspf(float x) {
  float ax = fabsf(x);
  return fmaxf(x, 0.0f) + __logf(1.0f + __expf(-ax)) - LN2F;
}

__device__ __forceinline__ unsigned short f2bf(float x) {
  return (unsigned short)((__float_as_uint(x) + 0x8000u) >> 16);  // RTN, <=0.5ulp
}

__device__ __forceinline__ unsigned short f2bf_ne(float x) {  // RTNE for weight prep
  unsigned int u = __float_as_uint(x);
  u += 0x7fffu + ((u >> 16) & 1u);
  return (unsigned short)(u >> 16);
}

__device__ __forceinline__ void dma16(const void* g, void* l) {
  __builtin_amdgcn_global_load_lds((gas1_t)(unsigned long long)g,
                                   (las3_t)(unsigned long long)l, 16, 0, 0);
}

// 16-wave block DMA: 32KB -> 2KB/wave, 16KB -> 1KB/wave
__device__ __forceinline__ void dma32k(const unsigned short* g, unsigned short* l,
                                       int w, int lane) {
  const char* gb = (const char*)g + w * 2048 + lane * 16;
  char* lb = (char*)l + w * 2048;
  dma16(gb, lb);
  dma16(gb + 1024, lb + 1024);
}
__device__ __forceinline__ void dma16k(const unsigned short* g, unsigned short* l,
                                       int w, int lane) {
  dma16((const char*)g + w * 1024 + lane * 16, (char*)l + w * 1024);
}

// ---------------------------------------------------------------------------
// S-path: LDS-hist radix sort (no global atomics) + gather
// ---------------------------------------------------------------------------
__global__ __launch_bounds__(256) void hist_pass(const int* __restrict__ idx,
                                                 unsigned int* __restrict__ H,
                                                 int n2p, int C) {
  __shared__ unsigned int h[8192];
  int b = blockIdx.x, tid = threadIdx.x;
  for (int i = tid; i < 8192; i += 256) h[i] = 0;
  __syncthreads();
  int s = b * C, e = min(s + C, n2p);
  for (int i = s + tid; i < e; i += 256) atomicAdd(&h[idx[i]], 1u);
  __syncthreads();
  for (int i = tid; i < 8192; i += 256) H[(size_t)b * 8192 + i] = h[i];
}

__global__ __launch_bounds__(256) void col_scan(unsigned int* __restrict__ H,
                                                unsigned int* __restrict__ tot) {
  int a = blockIdx.x * 256 + threadIdx.x;
  unsigned int run = 0;
  for (int b = 0; b < NB; ++b) {
    unsigned int v = H[(size_t)b * 8192 + a];
    H[(size_t)b * 8192 + a] = run;
    run += v;
  }
  tot[a] = run;
}

__global__ __launch_bounds__(256) void scan_kernel(const unsigned int* __restrict__ cnt,
                                                   unsigned int* __restrict__ off, int NA) {
  int t = threadIdx.x;
  unsigned int local[32], s = 0;
#pragma unroll
  for (int i = 0; i < 32; ++i) { local[i] = cnt[t * 32 + i]; s += local[i]; }
  unsigned int v = s;
  int lane = t & 63, w = t >> 6;
#pragma unroll
  for (int o = 1; o < 64; o <<= 1) {
    unsigned int u = __shfl_up(v, o, 64);
    if (lane >= o) v += u;
  }
  __shared__ unsigned int wt4[4];
  if (lane == 63) wt4[w] = v;
  __syncthreads();
  unsigned int base = 0;
  for (int k = 0; k < w; ++k) base += wt4[k];
  unsigned int excl = base + v - s;
#pragma unroll
  for (int i = 0; i < 32; ++i) { off[t * 32 + i] = excl; excl += local[i]; }
  if (t == 255) off[NA] = excl;
}

__global__ __launch_bounds__(256) void place_pass(const int* __restrict__ idx,
                                                  const unsigned int* __restrict__ H,
                                                  const unsigned int* __restrict__ off,
                                                  unsigned int* __restrict__ pairid,
                                                  int P, int C) {
  __shared__ unsigned int pos[8192];
  int b = blockIdx.x, tid = threadIdx.x;
  for (int i = tid; i < 8192; i += 256)
    pos[i] = off[i] + H[(size_t)b * 8192 + i];
  __syncthreads();
  int n2p = 2 * P;
  int s = b * C, e = min(s + C, n2p);
  for (int i = s + tid; i < e; i += 256) {
    int a = idx[i];
    unsigned int p = atomicAdd(&pos[a], 1u);
    pairid[p] = (i >= P) ? (unsigned int)(i - P) : (unsigned int)i;
  }
}

// fully-predicated 8-deep gather: all loads issue every batch, no serial tail
__global__ __launch_bounds__(256) void gather_kernel(const float* __restrict__ radial,
                                                     const unsigned int* __restrict__ off,
                                                     const unsigned int* __restrict__ pairid,
                                                     float* __restrict__ S) {
  __shared__ float red[3][64];
  int a = blockIdx.x;
  int lane = threadIdx.x & 63, w = threadIdx.x >> 6;
  unsigned int b = off[a], e = off[a + 1];
  float acc = 0.0f;
  for (unsigned int base = b + w; base < e; base += 32) {
    unsigned int pp[8];
    float vv[8];
#pragma unroll
    for (int k = 0; k < 8; ++k) {
      unsigned int j = base + 4 * k;
      pp[k] = pairid[j < e ? j : b];       // clamped: always a valid address
    }
#pragma unroll
    for (int k = 0; k < 8; ++k) vv[k] = radial[(size_t)pp[k] * 64 + lane];
#pragma unroll
    for (int k = 0; k < 8; ++k) {
      unsigned int j = base + 4 * k;
      acc += (j < e) ? vv[k] : 0.0f;
    }
  }
  if (w > 0) red[w - 1][lane] = acc;
  __syncthreads();
  if (w == 0) {
    acc += red[0][lane] + red[1][lane] + red[2][lane];
    S[(size_t)a * 64 + lane] = acc;
  }
}

// ---------------------------------------------------------------------------
// Weight prep: fp32 W[k][n] -> bf16, transposed + XOR-swizzled 16B chunks.
// chunk(n,j) at pos = n*16 + (j^(n&15))  (gate: n*8 + (j^(n&7)))
// ---------------------------------------------------------------------------
struct PrepArgs {
  const float* src[80];
  int isgate[80];
};

__global__ __launch_bounds__(256) void prep_weights(PrepArgs A, unsigned short* __restrict__ Wt) {
  int m = blockIdx.x;
  const float* s = A.src[m];
  unsigned short* d = Wt + (size_t)m * 16384;
  if (!A.isgate[m]) {
    for (int it = 0; it < 8; ++it) {
      int q = threadIdx.x + it * 256;
      int n = q & 127, j = q >> 7;
      unsigned short tmp[8];
#pragma unroll
      for (int cc = 0; cc < 8; ++cc) tmp[cc] = f2bf_ne(s[(8 * j + cc) * 128 + n]);
      *(uint4*)(d + (n * 16 + (j ^ (n & 15))) * 8) = *(uint4*)tmp;
    }
  } else {
    for (int it = 0; it < 4; ++it) {
      int q = threadIdx.x + it * 256;
      int n = q & 127, j = q >> 7;
      unsigned short tmp[8];
#pragma unroll
      for (int cc = 0; cc < 8; ++cc) tmp[cc] = f2bf_ne(s[(8 * j + cc) * 128 + n]);
      *(uint4*)(d + (n * 8 + (j ^ (n & 7))) * 8) = *(uint4*)tmp;
    }
  }
}

struct BiasArgs {
  const float* p[17];
  int stride[17];
  const float* b_out;
};

__global__ __launch_bounds__(256) void pack_bias(BiasArgs B, float* __restrict__ dst) {
  int l = blockIdx.x;
  for (int i = threadIdx.x; i < 17 * 128; i += 256) {
    int s = i >> 7;
    dst[(size_t)l * 2304 + i] = B.p[s][l * B.stride[s] + (i & 127)];
  }
  if (threadIdx.x == 0) dst[(size_t)l * 2304 + 17 * 128] = B.b_out[l];
}

// ---------------------------------------------------------------------------
// Fused chain kernel: 1024 threads = 16 waves; wave (g,c): rows 16g..16g+15,
// cols 16c..16c+15. 256 blocks = 1/CU, 4 waves/SIMD.
// ---------------------------------------------------------------------------
struct ChainArgs {
  const float* feat_in;
  const float* S;
  const unsigned short* wt;      // 80 slots x 16384 shorts
  const float* bias_pack;        // 5 x 2304 floats
  float* feat_out;
  float* energy;
};

__device__ __forceinline__ void gemm128s(const unsigned short* sA_, const unsigned short* sW,
                                         int arow, int col0, int l16, int quad, float4v* acc) {
  const unsigned short* ar = sA_ + (arow + l16) * 136 + quad * 8;
  short8 a0 = *(const short8*)(ar);
  short8 a1 = *(const short8*)(ar + 32);
  short8 a2 = *(const short8*)(ar + 64);
  short8 a3 = *(const short8*)(ar + 96);
  const unsigned short* bb = sW + col0 * 128;
  *acc = __builtin_amdgcn_mfma_f32_16x16x32_bf16(a0, *(const short8*)(bb + ((quad + 0) ^ l16) * 8), *acc, 0, 0, 0);
  *acc = __builtin_amdgcn_mfma_f32_16x16x32_bf16(a1, *(const short8*)(bb + ((quad + 4) ^ l16) * 8), *acc, 0, 0, 0);
  *acc = __builtin_amdgcn_mfma_f32_16x16x32_bf16(a2, *(const short8*)(bb + ((quad + 8) ^ l16) * 8), *acc, 0, 0, 0);
  *acc = __builtin_amdgcn_mfma_f32_16x16x32_bf16(a3, *(const short8*)(bb + ((quad + 12) ^ l16) * 8), *acc, 0, 0, 0);
}

__device__ __forceinline__ void gemm64s(const unsigned short* sS_, const unsigned short* sW,
                                        int arow, int col0, int l16, int quad, float4v* acc) {
  const unsigned short* ar = sS_ + (arow + l16) * 72 + quad * 8;
  short8 a0 = *(const short8*)(ar);
  short8 a1 = *(const short8*)(ar + 32);
  int l8 = l16 & 7;
  const unsigned short* bb = sW + col0 * 64;
  *acc = __builtin_amdgcn_mfma_f32_16x16x32_bf16(a0, *(const short8*)(bb + ((quad + 0) ^ l8) * 8), *acc, 0, 0, 0);
  *acc = __builtin_amdgcn_mfma_f32_16x16x32_bf16(a1, *(const short8*)(bb + ((quad + 4) ^ l8) * 8), *acc, 0, 0, 0);
}

__device__ __forceinline__ void write_ssp_A(unsigned short* sA_, const float4v v,
                                            int arow, int col0, int quad) {
#pragma unroll
  for (int r = 0; r < 4; ++r)
    sA_[(arow + quad * 4 + r) * 136 + col0] = f2bf(sspf(v[r]));
}

__global__ __launch_bounds__(1024, 4) void chain_kernel(ChainArgs A) {
  __shared__ __align__(16) unsigned short swb[2][16384];   // 64 KB weight dbuf
  __shared__ __align__(16) unsigned short sA[2][32 * 136];
  __shared__ __align__(16) unsigned short sS[32 * 72];
  __shared__ float sBias[2304];
  __shared__ float sE[32];

  const int tid  = threadIdx.x;
  const int row0 = blockIdx.x * 32;
  const int lane = tid & 63;
  const int w    = tid >> 6;       // 0..15
  const int g    = w >> 3;         // row group 0..1
  const int c    = w & 7;          // col 16-chunk 0..7
  const int l16  = lane & 15;
  const int quad = lane >> 4;
  const int arow = 16 * g;
  const int col0 = 16 * c + l16;

  dma16k(A.wt, swb[0], w, lane);   // module-0 gate

  for (int i = tid; i < 32 * 64; i += 1024) {
    int r = i >> 6, k = i & 63;
    sS[r * 72 + k] = f2bf(A.S[(size_t)(row0 + r) * 64 + k]);
  }
  for (int i = tid; i < 32 * 128; i += 1024) {
    int r = i >> 7, k = i & 127;
    sA[0][r * 136 + k] = f2bf(sspf(A.feat_in[(size_t)(row0 + r) * 128 + k]));
  }
  float4v ff;
#pragma unroll
  for (int r = 0; r < 4; ++r)
    ff[r] = A.feat_in[(size_t)(row0 + arow + quad * 4 + r) * 128 + col0];
  if (tid < 32) sE[tid] = 0.0f;
  __syncthreads();

  const float4v Z = {0.f, 0.f, 0.f, 0.f};
  float4v gG, fm, xf, t4;
  float p0 = 0.f, p1 = 0.f, p2 = 0.f, p3 = 0.f, bsum = 0.f;

#pragma unroll 1
  for (int l = 0; l < 5; ++l) {
    const size_t slot0 = (size_t)l * 16 * 16384;

    // ---- t=0: gate GEMM; DMA W_J; stage biases
    dma32k(A.wt + slot0 + 16384, swb[1], w, lane);
    for (int i = tid; i < 2304; i += 1024) sBias[i] = A.bias_pack[(size_t)l * 2304 + i];
    gG = Z;
    gemm64s(sS, swb[0], arow, col0, l16, quad, &gG);
    __syncthreads();

    // ---- t=1: W_J -> fm
    dma32k(A.wt + slot0 + 2 * 16384, swb[0], w, lane);
    fm = Z;
    gemm128s(sA[0], swb[1], arow, col0, l16, quad, &fm);
    {
      float bv = sBias[0 * 128 + col0];
#pragma unroll
      for (int r = 0; r < 4; ++r) fm[r] = sspf(fm[r] + bv);
    }
    __syncthreads();

    // ---- t=2: W_I; proto = fm*gG + ssp(t4+b) -> sA1
    dma32k(A.wt + slot0 + 3 * 16384, swb[1], w, lane);
    t4 = Z;
    gemm128s(sA[0], swb[0], arow, col0, l16, quad, &t4);
    {
      float bv = sBias[1 * 128 + col0];
#pragma unroll
      for (int r = 0; r < 4; ++r) xf[r] = fm[r] * gG[r] + sspf(t4[r] + bv);
    }
    write_ssp_A(sA[1], xf, arow, col0, quad);
    __syncthreads();

    // ---- t=3..8: ri chain x3
#pragma unroll
    for (int jj = 0; jj < 3; ++jj) {
      const int th = 3 + 2 * jj;
      dma32k(A.wt + slot0 + (size_t)(th + 1) * 16384, swb[th & 1 ? 0 : 1], w, lane);
      t4 = Z;
      gemm128s(sA[1], swb[th & 1], arow, col0, l16, quad, &t4);
      {
        float bv = sBias[(th - 1) * 128 + col0];
#pragma unroll
        for (int r = 0; r < 4; ++r) t4[r] += bv;
      }
      write_ssp_A(sA[0], t4, arow, col0, quad);
      __syncthreads();

      const int tx = th + 1;
      dma32k(A.wt + slot0 + (size_t)(tx + 1) * 16384, swb[tx & 1 ? 0 : 1], w, lane);
      t4 = Z;
      gemm128s(sA[0], swb[tx & 1], arow, col0, l16, quad, &t4);
      {
        float bv = sBias[(tx - 1) * 128 + col0];
#pragma unroll
        for (int r = 0; r < 4; ++r) xf[r] += t4[r] + bv;
      }
      write_ssp_A(sA[1], xf, arow, col0, quad);
      __syncthreads();
    }

    // ---- t=9: W_int: xf = ff*gvec + t4 + b  (read sA1/swb1, write sA0)
    dma32k(A.wt + slot0 + 10 * 16384, swb[0], w, lane);
    t4 = Z;
    gemm128s(sA[1], swb[1], arow, col0, l16, quad, &t4);
    {
      float bv = sBias[8 * 128 + col0];
      float gv = sBias[15 * 128 + col0];
#pragma unroll
      for (int r = 0; r < 4; ++r) xf[r] = ff[r] * gv + t4[r] + bv;
    }
    write_ssp_A(sA[0], xf, arow, col0, quad);
    __syncthreads();

    // ---- t=10..13: ra chain x2
#pragma unroll
    for (int jj = 0; jj < 2; ++jj) {
      const int th = 10 + 2 * jj;
      dma32k(A.wt + slot0 + (size_t)(th + 1) * 16384, swb[th & 1 ? 0 : 1], w, lane);
      t4 = Z;
      gemm128s(sA[0], swb[th & 1], arow, col0, l16, quad, &t4);
      {
        float bv = sBias[(th - 1) * 128 + col0];
#pragma unroll
        for (int r = 0; r < 4; ++r) t4[r] += bv;
      }
      write_ssp_A(sA[1], t4, arow, col0, quad);
      __syncthreads();

      const int tx = th + 1;
      dma32k(A.wt + slot0 + (size_t)(tx + 1) * 16384, swb[tx & 1 ? 0 : 1], w, lane);
      t4 = Z;
      gemm128s(sA[1], swb[tx & 1], arow, col0, l16, quad, &t4);
      {
        float bv = sBias[(tx - 1) * 128 + col0];
#pragma unroll
        for (int r = 0; r < 4; ++r) xf[r] += t4[r] + bv;
      }
      write_ssp_A(sA[0], xf, arow, col0, quad);
      __syncthreads();
    }

    // xf is feat2
    ff = xf;
    if (l == 4) {
#pragma unroll
      for (int r = 0; r < 4; ++r)
        A.feat_out[(size_t)(row0 + arow + quad * 4 + r) * 128 + col0] = xf[r];
    }

    // ---- t=14: ro_W1 (read sA0/swb0, write sA1)
    dma32k(A.wt + slot0 + 15 * 16384, swb[1], w, lane);
    t4 = Z;
    gemm128s(sA[0], swb[0], arow, col0, l16, quad, &t4);
    {
      float bv = sBias[13 * 128 + col0];
#pragma unroll
      for (int r = 0; r < 4; ++r) t4[r] += bv;
    }
    write_ssp_A(sA[1], t4, arow, col0, quad);
    __syncthreads();

    // ---- t=15: ro_W2; energy; DMA next gate -> swb0
    if (l < 4) dma16k(A.wt + slot0 + 16 * 16384, swb[0], w, lane);
    t4 = Z;
    gemm128s(sA[1], swb[1], arow, col0, l16, quad, &t4);
    {
      float bv = sBias[14 * 128 + col0];
      float wv = sBias[16 * 128 + col0];
      p0 += sspf(xf[0] + t4[0] + bv) * wv;
      p1 += sspf(xf[1] + t4[1] + bv) * wv;
      p2 += sspf(xf[2] + t4[2] + bv) * wv;
      p3 += sspf(xf[3] + t4[3] + bv) * wv;
    }
    bsum += sBias[17 * 128];
    __syncthreads();
  }

  // ---- energy reduction (within 16-lane groups, then across 8 c-waves)
#pragma unroll
  for (int o = 1; o < 16; o <<= 1) {
    p0 += __shfl_xor(p0, o, 64);
    p1 += __shfl_xor(p1, o, 64);
    p2 += __shfl_xor(p2, o, 64);
    p3 += __shfl_xor(p3, o, 64);
  }
  if (l16 == 0) {
    atomicAdd(&sE[arow + quad * 4 + 0], p0);
    atomicAdd(&sE[arow + quad * 4 + 1], p1);
    atomicAdd(&sE[arow + quad * 4 + 2], p2);
    atomicAdd(&sE[arow + quad * 4 + 3], p3);
  }
  __syncthreads();
  if (tid < 32) A.energy[row0 + tid] = sE[tid] + bsum;
}

// ---------------------------------------------------------------------------
extern "C" void kernel_launch(void* const* d_in, const int* in_sizes, int n_in,
                              void* d_out, int out_size, void* d_ws, size_t ws_size,
                              hipStream_t stream) {
  const float* features = (const float*)d_in[1];
  const float* radial   = (const float*)d_in[2];
  const int*   idx12    = (const int*)  d_in[3];
  const float* W_I    = (const float*)d_in[4];
  const float* b_I    = (const float*)d_in[5];
  const float* W_J    = (const float*)d_in[6];
  const float* b_J    = (const float*)d_in[7];
  const float* W_gate = (const float*)d_in[8];
  const float* gvec   = (const float*)d_in[9];
  const float* W_int  = (const float*)d_in[10];
  const float* b_int  = (const float*)d_in[11];
  const float* ri_W1  = (const float*)d_in[12];
  const float* ri_b1  = (const float*)d_in[13];
  const float* ri_W2  = (const float*)d_in[14];
  const float* ri_b2  = (const float*)d_in[15];
  const float* ra_W1  = (const float*)d_in[16];
  const float* ra_b1  = (const float*)d_in[17];
  const float* ra_W2  = (const float*)d_in[18];
  const float* ra_b2  = (const float*)d_in[19];
  const float* ro_W1  = (const float*)d_in[20];
  const float* ro_b1  = (const float*)d_in[21];
  const float* ro_W2  = (const float*)d_in[22];
  const float* ro_b2  = (const float*)d_in[23];
  const float* W_out  = (const float*)d_in[24];
  const float* b_out  = (const float*)d_in[25];

  const int N = in_sizes[1] / 128;   // 8192
  const int P = in_sizes[3] / 2;     // 400000
  const int L = in_sizes[25];        // 5
  const int n2p = 2 * P;
  const int C = (n2p + NB - 1) / NB;

  // ws layout: S | bias_pack | Wt | H | tot | off | pairid
  float* S = (float*)d_ws;
  float* bias_pack = S + (size_t)N * 64;
  unsigned short* Wt = (unsigned short*)(bias_pack + 5 * 2304);
  unsigned int* H      = (unsigned int*)(Wt + (size_t)80 * 16384);
  unsigned int* tot    = H + (size_t)NB * 8192;
  unsigned int* off    = tot + N;
  unsigned int* pairid = off + N + 4;

  // ---- weight prep (consumption order: gate,WJ,WI,ri*6,Wint,ra*4,ro*2)
  PrepArgs pa;
  for (int l = 0; l < L; ++l) {
    const float* fx[16] = {
      W_gate + l * 8192,
      W_J + l * 16384, W_I + l * 16384,
      ri_W1 + (l * 3 + 0) * 16384, ri_W2 + (l * 3 + 0) * 16384,
      ri_W1 + (l * 3 + 1) * 16384, ri_W2 + (l * 3 + 1) * 16384,
      ri_W1 + (l * 3 + 2) * 16384, ri_W2 + (l * 3 + 2) * 16384,
      W_int + l * 16384,
      ra_W1 + (l * 2 + 0) * 16384, ra_W2 + (l * 2 + 0) * 16384,
      ra_W1 + (l * 2 + 1) * 16384, ra_W2 + (l * 2 + 1) * 16384,
      ro_W1 + l * 16384, ro_W2 + l * 16384 };
    for (int t = 0; t < 16; ++t) { pa.src[l * 16 + t] = fx[t]; pa.isgate[l * 16 + t] = (t == 0); }
  }
  prep_weights<<<80, 256, 0, stream>>>(pa, Wt);

  BiasArgs ba;
  const float* bp[17] = { b_J, b_I,
    ri_b1, ri_b2, ri_b1 + 128, ri_b2 + 128, ri_b1 + 256, ri_b2 + 256,
    b_int, ra_b1, ra_b2, ra_b1 + 128, ra_b2 + 128, ro_b1, ro_b2, gvec, W_out };
  int st[17] = {128,128, 384,384,384,384,384,384, 128, 256,256,256,256, 128,128,128,128};
  for (int q = 0; q < 17; ++q) { ba.p[q] = bp[q]; ba.stride[q] = st[q]; }
  ba.b_out = b_out;
  pack_bias<<<5, 256, 0, stream>>>(ba, bias_pack);

  // ---- S via LDS-hist sort + gather (no global atomics)
  hist_pass<<<NB, 256, 0, stream>>>(idx12, H, n2p, C);
  col_scan<<<32, 256, 0, stream>>>(H, tot);
  scan_kernel<<<1, 256, 0, stream>>>(tot, off, N);
  place_pass<<<NB, 256, 0, stream>>>(idx12, H, off, pairid, P, C);
  gather_kernel<<<N, 256, 0, stream>>>(radial, off, pairid, S);

  // ---- fused 5-module chain
  ChainArgs ca;
  ca.feat_in   = features;
  ca.S         = S;
  ca.wt        = Wt;
  ca.bias_pack = bias_pack;
  ca.energy    = (float*)d_out;
  ca.feat_out  = (float*)d_out + N;
  chain_kernel<<<N / 32, 1024, 0, stream>>>(ca);
}